// Round 1
// baseline (1804.526 us; speedup 1.0000x reference)
//
#include <hip/hip_runtime.h>
#include <hip/hip_bf16.h>
#include <cstdint>

using bf16 = __hip_bfloat16;
typedef __attribute__((ext_vector_type(8))) short bfrag;   // 8 x bf16 (4 VGPRs)
typedef __attribute__((ext_vector_type(4))) float ffrag;   // 4 x f32 acc

#define DEV __device__ __forceinline__

DEV float wred_sum(float v) {
#pragma unroll
  for (int o = 32; o > 0; o >>= 1) v += __shfl_xor(v, o, 64);
  return v;
}
DEV float bred_sum(float v) {
  __shared__ float r[4];
  int w = threadIdx.x >> 6, l = threadIdx.x & 63;
  v = wred_sum(v);
  __syncthreads();
  if (l == 0) r[w] = v;
  __syncthreads();
  return r[0] + r[1] + r[2] + r[3];
}
DEV float bred_max(float v) {
  __shared__ float rm[4];
  int w = threadIdx.x >> 6, l = threadIdx.x & 63;
#pragma unroll
  for (int o = 32; o > 0; o >>= 1) v = fmaxf(v, __shfl_xor(v, o, 64));
  __syncthreads();
  if (l == 0) rm[w] = v;
  __syncthreads();
  return fmaxf(fmaxf(rm[0], rm[1]), fmaxf(rm[2], rm[3]));
}
DEV float gelu_f(float x) {  // jax.nn.gelu approximate=True
  float x3 = x * x * x;
  return 0.5f * x * (1.0f + tanhf(0.7978845608028654f * (x + 0.044715f * x3)));
}

// ---------------------------------------------------------------- GEMM (NT)
// C[m,n] = sum_k A[m,k] * B[n,k]   (A row-major [M,K], B row-major [N,K])
struct GemmP {
  const bf16* A = nullptr; const bf16* B = nullptr; void* C = nullptr;
  const float* bias = nullptr; const float* rowvec = nullptr;
  const float* p1 = nullptr; const float* p2 = nullptr;
  int K = 0, lda = 0, ldb = 0, ldc = 0, inner = 1, mode = 0;
  long sA0 = 0, sA1 = 0, sB0 = 0, sB1 = 0, sC0 = 0, sC1 = 0, sb0 = 0, sb1 = 0, sRV0 = 0;
  float scale = 1.f;
};
// modes: 0 bf16 store | 1 f32 store | 2 f32 += p1[m]*p2[m]*(v) | 3 bf16 gelu
//        4 bf16 elu+1 | 5 bf16 v/rowvec[z,m]

template <int BM, int BN, int WM, int WN>
__global__ __launch_bounds__(256)
void gemm_nt(GemmP p) {
  __shared__ bf16 smem[(BM + BN) * 32];
  const int tid = threadIdx.x;
  const int z = blockIdx.z;
  const int z0 = z % p.inner, z1 = z / p.inner;
  const bf16* A = p.A + (long)z0 * p.sA0 + (long)z1 * p.sA1;
  const bf16* Bp = p.B + (long)z0 * p.sB0 + (long)z1 * p.sB1;
  const int m0 = blockIdx.x * BM, n0 = blockIdx.y * BN;
  const int wave = tid >> 6, lane = tid & 63;
  const int wrow = wave / WN, wcol = wave % WN;
  const int fr = lane & 15, quad = lane >> 4;
  ffrag acc[4][4] = {};
  constexpr int CH_A = BM * 4;
  constexpr int NIT = (BM + BN) * 4 / 256;
  for (int k0 = 0; k0 < p.K; k0 += 32) {
#pragma unroll
    for (int it = 0; it < NIT; ++it) {
      int idx = it * 256 + tid;
      const bf16* g;
      if (idx < CH_A) {
        int r = idx >> 2, c = idx & 3;
        g = A + (long)(m0 + r) * p.lda + k0 + c * 8;
      } else {
        int j = idx - CH_A;
        int r = j >> 2, c = j & 3;
        g = Bp + (long)(n0 + r) * p.ldb + k0 + c * 8;
      }
      __builtin_amdgcn_global_load_lds(
          (const __attribute__((address_space(1))) void*)g,
          (__attribute__((address_space(3))) void*)(smem + idx * 8), 16, 0, 0);
    }
    __syncthreads();
    bfrag af[4], bfb[4];
#pragma unroll
    for (int t = 0; t < 4; ++t)
      af[t] = *(const bfrag*)(smem + ((wrow * 64 + t * 16 + fr) * 32 + quad * 8));
#pragma unroll
    for (int t = 0; t < 4; ++t)
      bfb[t] = *(const bfrag*)(smem + (BM * 32 + (wcol * 64 + t * 16 + fr) * 32 + quad * 8));
#pragma unroll
    for (int ti = 0; ti < 4; ++ti)
#pragma unroll
      for (int tj = 0; tj < 4; ++tj)
        acc[ti][tj] = __builtin_amdgcn_mfma_f32_16x16x32_bf16(af[ti], bfb[tj], acc[ti][tj], 0, 0, 0);
    __syncthreads();
  }
  const int mbase = m0 + wrow * 64, nbase = n0 + wcol * 64;
  const long zc = (long)z0 * p.sC0 + (long)z1 * p.sC1;
  const long zb = (long)z0 * p.sb0 + (long)z1 * p.sb1;
#pragma unroll
  for (int ti = 0; ti < 4; ++ti) {
#pragma unroll
    for (int tj = 0; tj < 4; ++tj) {
#pragma unroll
      for (int r = 0; r < 4; ++r) {
        int m = mbase + ti * 16 + quad * 4 + r;
        int n = nbase + tj * 16 + fr;
        float v = acc[ti][tj][r] * p.scale;
        if (p.bias) v += p.bias[zb + n];
        long ci = zc + (long)m * p.ldc + n;
        if (p.mode == 0) ((bf16*)p.C)[ci] = __float2bfloat16(v);
        else if (p.mode == 1) ((float*)p.C)[ci] = v;
        else if (p.mode == 2) {
          float w = p.p1[(long)m * 4] * p.p2[(long)m * 2];
          ((float*)p.C)[ci] += w * v;
        } else if (p.mode == 3) ((bf16*)p.C)[ci] = __float2bfloat16(gelu_f(v));
        else if (p.mode == 4) ((bf16*)p.C)[ci] = __float2bfloat16(v > 0.f ? v + 1.f : __expf(v));
        else {
          float d = p.rowvec[(long)blockIdx.z * p.sRV0 + m];
          ((bf16*)p.C)[ci] = __float2bfloat16(v / d);
        }
      }
    }
  }
}

static void launch_gemm(hipStream_t st, int cfg, int M, int N, int batch, const GemmP& g) {
  dim3 bs(256), gr;
  if (cfg == 0) { gr = dim3(M / 128, N / 128, batch); gemm_nt<128, 128, 2, 2><<<gr, bs, 0, st>>>(g); }
  else if (cfg == 1) { gr = dim3(M / 256, N / 64, batch); gemm_nt<256, 64, 4, 1><<<gr, bs, 0, st>>>(g); }
  else { gr = dim3(M / 64, N / 256, batch); gemm_nt<64, 256, 1, 4><<<gr, bs, 0, st>>>(g); }
}

// ---------------------------------------------------------------- utility kernels
__global__ void f2b_k(const float* in, bf16* outp, long n) {
  long i = (long)blockIdx.x * 256 + threadIdx.x;
  if (i < n) outp[i] = __float2bfloat16(in[i]);
}

// fp32 [z][R][C] -> bf16 [z][C][R]
__global__ void transpose_conv_k(const float* in, bf16* outp, int R, int C) {
  __shared__ float t[32][33];
  long zo = (long)blockIdx.z * R * C;
  int c0 = blockIdx.x * 32, r0 = blockIdx.y * 32;
  int tx = threadIdx.x & 31, ty = threadIdx.x >> 5;
#pragma unroll
  for (int i = 0; i < 32; i += 8)
    t[ty + i][tx] = in[zo + (long)(r0 + ty + i) * C + c0 + tx];
  __syncthreads();
#pragma unroll
  for (int i = 0; i < 32; i += 8)
    outp[zo + (long)(c0 + ty + i) * R + r0 + tx] = __float2bfloat16(t[tx][ty + i]);
}

// bf16 strided [z](R x C, row stride rs) -> bf16 [z][C][R]
__global__ void transpose_bf16_k(const bf16* in, bf16* outp, int R, int C, int rs,
                                 int inner, long is0, long is1) {
  __shared__ bf16 t[32][33];
  int z = blockIdx.z;
  long zo = (long)(z % inner) * is0 + (long)(z / inner) * is1;
  int c0 = blockIdx.x * 32, r0 = blockIdx.y * 32;
  int tx = threadIdx.x & 31, ty = threadIdx.x >> 5;
#pragma unroll
  for (int i = 0; i < 32; i += 8)
    t[ty + i][tx] = in[zo + (long)(r0 + ty + i) * rs + c0 + tx];
  __syncthreads();
  long ob = (long)z * R * C;
#pragma unroll
  for (int i = 0; i < 32; i += 8)
    outp[ob + (long)(c0 + ty + i) * R + r0 + tx] = t[tx][ty + i];
}

__global__ void softmax_rows_k(bf16* sc) {  // N = 1024, in-place
  long row = blockIdx.x;
  bf16* p = sc + row * 1024;
  int tid = threadIdx.x;
  float v[4];
  float lm = -1e30f;
#pragma unroll
  for (int i = 0; i < 4; ++i) { v[i] = __bfloat162float(p[tid + i * 256]); lm = fmaxf(lm, v[i]); }
  float m = bred_max(lm);
  float ls = 0.f;
#pragma unroll
  for (int i = 0; i < 4; ++i) { v[i] = __expf(v[i] - m); ls += v[i]; }
  float inv = 1.0f / bred_sum(ls);
#pragma unroll
  for (int i = 0; i < 4; ++i) p[tid + i * 256] = __float2bfloat16(v[i] * inv);
}

__global__ void ln_act_k(const float* in, const float* gamma, const float* beta,
                         bf16* outp, int N, int act, int rows_per_seg) {
  long row = blockIdx.x;
  const float* ip = in + row * N;
  bf16* op = outp + row * N;
  long go = (row / rows_per_seg) * N;
  const float* gp = gamma + go;
  const float* bp = beta + go;
  int tid = threadIdx.x;
  float ls = 0.f;
  for (int c = tid; c < N; c += 256) ls += ip[c];
  float mean = bred_sum(ls) / N;
  float lv = 0.f;
  for (int c = tid; c < N; c += 256) { float d = ip[c] - mean; lv += d * d; }
  float rstd = rsqrtf(bred_sum(lv) / N + 1e-5f);
  for (int c = tid; c < N; c += 256) {
    float v = (ip[c] - mean) * rstd * gp[c] + bp[c];
    v = act ? gelu_f(v) : fmaxf(v, 0.f);
    op[c] = __float2bfloat16(v);
  }
}

__global__ void tokimp_k(const float* x, const float* spw, const float* spb, float* outp) {
  int row = blockIdx.x * 4 + (threadIdx.x >> 6);
  int l = threadIdx.x & 63;
  const float* xp = x + (long)row * 1024;
  float a = 0.f;
  for (int c = l; c < 1024; c += 64) a += xp[c] * spw[c];
  a = wred_sum(a);
  if (l == 0) outp[row] = a + spb[0];
}

__global__ void topk_k(const float* timp, int* outp) {
  __shared__ float vals[1024];
  __shared__ float wv[4];
  __shared__ int wi[4];
  int b = blockIdx.x, tid = threadIdx.x;
  for (int c = tid; c < 1024; c += 256) vals[c] = timp[b * 1024 + c];
  __syncthreads();
  for (int t = 0; t < 10; ++t) {
    float bv = -3.0e38f; int bi = 1 << 30;
    for (int c = tid; c < 1024; c += 256) {
      float v = vals[c];
      if (v > bv || (v == bv && c < bi)) { bv = v; bi = c; }
    }
#pragma unroll
    for (int o = 32; o > 0; o >>= 1) {
      float ov = __shfl_xor(bv, o, 64); int oi = __shfl_xor(bi, o, 64);
      if (ov > bv || (ov == bv && oi < bi)) { bv = ov; bi = oi; }
    }
    int w = tid >> 6, l = tid & 63;
    if (l == 0) { wv[w] = bv; wi[w] = bi; }
    __syncthreads();
    if (tid == 0) {
      float fv = wv[0]; int fi = wi[0];
      for (int ww = 1; ww < 4; ++ww)
        if (wv[ww] > fv || (wv[ww] == fv && wi[ww] < fi)) { fv = wv[ww]; fi = wi[ww]; }
      outp[b * 16 + t] = fi;
      vals[fi] = -3.0e38f;
    }
    __syncthreads();
  }
}

__global__ void vsum_k(const bf16* v, float* vsum) {
  __shared__ float red[4][64];
  int z = blockIdx.x, b = z >> 4, h = z & 15;
  const bf16* vp = v + (long)b * 1048576 + h * 64;
  int d = threadIdx.x & 63, sg = threadIdx.x >> 6;
  float s = 0.f;
  for (int srow = sg; srow < 1024; srow += 4) s += __bfloat162float(vp[(long)srow * 1024 + d]);
  red[sg][d] = s;
  __syncthreads();
  if (sg == 0) vsum[z * 64 + d] = red[0][d] + red[1][d] + red[2][d] + red[3][d];
}

// expert-0 sparse attention: softmax(scores * 10-hot-mask) @ V, algebraically reduced
__global__ void sparse_attn_k(const bf16* q, const bf16* k, const bf16* v,
                              const float* vsum, const int* topidx, bf16* merged) {
  __shared__ float kt[10][64], vt[10][64], vs[64], vts[64];
  int z = blockIdx.y, b = z >> 4, h = z & 15;
  int tid = threadIdx.x;
  const int* tix = topidx + b * 16;
  for (int t = tid; t < 640; t += 256) {
    int tt = t >> 6, d = t & 63;
    long src = ((long)b * 1024 + tix[tt]) * 1024 + h * 64 + d;
    kt[tt][d] = __bfloat162float(k[src]);
    vt[tt][d] = __bfloat162float(v[src]);
  }
  if (tid < 64) vs[tid] = vsum[z * 64 + tid];
  __syncthreads();
  if (tid < 64) {
    float s = 0.f;
#pragma unroll
    for (int t = 0; t < 10; ++t) s += vt[t][tid];
    vts[tid] = s;
  }
  __syncthreads();
  int wave = tid >> 6, lane = tid & 63;
  int sq = blockIdx.x * 4 + wave;
  long qi = ((long)b * 1024 + sq) * 1024 + h * 64 + lane;
  float qd = __bfloat162float(q[qi]);
  float sc[10];
#pragma unroll
  for (int t = 0; t < 10; ++t) sc[t] = wred_sum(qd * kt[t][lane]) * 0.125f;
  float m = 0.f;
#pragma unroll
  for (int t = 0; t < 10; ++t) m = fmaxf(m, sc[t]);
  float e[10], se = 0.f;
#pragma unroll
  for (int t = 0; t < 10; ++t) { e[t] = __expf(sc[t] - m); se += e[t]; }
  float em = __expf(-m);
  float Z = 1014.f * em + se;
  float o = em * (vs[lane] - vts[lane]);
#pragma unroll
  for (int t = 0; t < 10; ++t) o += e[t] * vt[t][lane];
  merged[qi] = __float2bfloat16(o / Z);
}

__global__ void ksum_k(const bf16* kpsi, float* ksum) {
  int z = blockIdx.x, tid = threadIdx.x;
  const bf16* kp = kpsi + (long)z * 262144;
  float s = 0.f;
  for (int l = 0; l < 1024; ++l) s += __bfloat162float(kp[(long)l * 256 + tid]);
  ksum[z * 256 + tid] = s;
}

__global__ void den_k(const bf16* qphi, const float* ksum, float* den) {
  int r = blockIdx.x * 4 + (threadIdx.x >> 6);
  int l = threadIdx.x & 63;
  int z = r >> 10;
  const bf16* qp = qphi + (long)r * 256;
  const float* ks = ksum + z * 256;
  float a = 0.f;
  for (int c = l; c < 256; c += 64) a += __bfloat162float(qp[c]) * ks[c];
  a = wred_sum(a);
  if (l == 0) den[r] = a + 1e-8f;
}

__global__ void dwconv_k(const float* x, const float* dw, bf16* outp) {
  long i = (long)blockIdx.x * 256 + threadIdx.x;
  int d = (int)(i & 1023);
  long row = i >> 10;
  int s = (int)(row & 1023);
  float a = x[i] * dw[1024 + d];
  if (s > 0) a += x[i - 1024] * dw[d];
  if (s < 1023) a += x[i + 1024] * dw[2048 + d];
  outp[i] = __float2bfloat16(a);
}

__global__ void router1_k(const bf16* h1, const float* w, const float* bias, float* outp) {
  int row = blockIdx.x * 4 + (threadIdx.x >> 6);
  int l = threadIdx.x & 63;
  const bf16* hp = h1 + (long)row * 512;
  float a0 = 0, a1 = 0, a2 = 0, a3 = 0;
  for (int c = l; c < 512; c += 64) {
    float hv = __bfloat162float(hp[c]);
    const float* wp = w + c * 4;
    a0 += hv * wp[0]; a1 += hv * wp[1]; a2 += hv * wp[2]; a3 += hv * wp[3];
  }
  a0 = wred_sum(a0); a1 = wred_sum(a1); a2 = wred_sum(a2); a3 = wred_sum(a3);
  a0 += bias[0]; a1 += bias[1]; a2 += bias[2]; a3 += bias[3];
  float m = fmaxf(fmaxf(a0, a1), fmaxf(a2, a3));
  float e0 = __expf(a0 - m), e1 = __expf(a1 - m), e2 = __expf(a2 - m), e3 = __expf(a3 - m);
  float inv = 1.f / (e0 + e1 + e2 + e3);
  if (l == 0) {
    float* op = outp + (long)row * 4;
    op[0] = e0 * inv; op[1] = e1 * inv; op[2] = e2 * inv; op[3] = e3 * inv;
  }
}

__global__ void router2_k(const bf16* h2, const float* w, const float* bias, float* outp,
                          int rows_per_seg) {
  int row = blockIdx.x * 4 + (threadIdx.x >> 6);
  int l = threadIdx.x & 63;
  int seg = row / rows_per_seg;
  const float* wp = w + (long)seg * 512;
  const float* bp = bias + (long)seg * 2;
  const bf16* hp = h2 + (long)row * 256;
  float a0 = 0, a1 = 0;
  for (int c = l; c < 256; c += 64) {
    float hv = __bfloat162float(hp[c]);
    a0 += hv * wp[c * 2]; a1 += hv * wp[c * 2 + 1];
  }
  a0 = wred_sum(a0); a1 = wred_sum(a1);
  a0 += bp[0]; a1 += bp[1];
  float m = fmaxf(a0, a1);
  float e0 = __expf(a0 - m), e1 = __expf(a1 - m);
  float inv = 1.f / (e0 + e1);
  if (l == 0) { outp[(long)row * 2] = e0 * inv; outp[(long)row * 2 + 1] = e1 * inv; }
}

// ---------------------------------------------------------------- host
extern "C" void kernel_launch(void* const* d_in, const int* in_sizes, int n_in,
                              void* d_out, int out_size, void* d_ws, size_t ws_size,
                              hipStream_t stream) {
  const float* x = (const float*)d_in[0];
  const float* w_qkvo = (const float*)d_in[1];
  const float* b_qkvo = (const float*)d_in[2];
  const float* sp_w = (const float*)d_in[3];
  const float* sp_b = (const float*)d_in[4];
  const float* phi_w = (const float*)d_in[5];
  const float* phi_b = (const float*)d_in[6];
  const float* psi_w = (const float*)d_in[7];
  const float* psi_b = (const float*)d_in[8];
  const float* conv_dw = (const float*)d_in[9];
  const float* conv_pw = (const float*)d_in[10];
  const float* fus_w = (const float*)d_in[11];
  const float* fus_b = (const float*)d_in[12];
  const float* sub_w1 = (const float*)d_in[13];
  const float* sub_b1 = (const float*)d_in[14];
  const float* sub_g = (const float*)d_in[15];
  const float* sub_be = (const float*)d_in[16];
  const float* sub_w2 = (const float*)d_in[17];
  const float* sub_b2 = (const float*)d_in[18];
  const float* r1_w1 = (const float*)d_in[19];
  const float* r1_b1 = (const float*)d_in[20];
  const float* r1_g = (const float*)d_in[21];
  const float* r1_be = (const float*)d_in[22];
  const float* r1_w2 = (const float*)d_in[23];
  const float* r1_b2 = (const float*)d_in[24];
  const float* r2_w1 = (const float*)d_in[25];
  const float* r2_b1 = (const float*)d_in[26];
  const float* r2_g = (const float*)d_in[27];
  const float* r2_be = (const float*)d_in[28];
  const float* r2_w2 = (const float*)d_in[29];
  const float* r2_b2 = (const float*)d_in[30];
  (void)in_sizes; (void)n_in; (void)ws_size;

  char* ws = (char*)d_ws;
  size_t off = 0;
  auto take = [&](size_t bytes) { void* p = ws + off; off += (bytes + 255) & ~(size_t)255; return p; };

  const long EL2M = 2097152;  // 2048*1024
  const long EL1M = 1048576;  // 1024*1024

  bf16* XB      = (bf16*)take((size_t)EL2M * 2);
  bf16* WQKVOT  = (bf16*)take((size_t)16 * EL1M * 2);
  bf16* SUBW1T  = (bf16*)take((size_t)8 * EL1M * 2);
  bf16* SUBW2T  = (bf16*)take((size_t)8 * EL1M * 2);
  bf16* CONVPWT = (bf16*)take((size_t)EL1M * 2);
  bf16* FUSWT   = (bf16*)take((size_t)EL2M * 2);
  bf16* R1W1T   = (bf16*)take((size_t)512 * 1024 * 2);
  bf16* R2W1T   = (bf16*)take((size_t)4 * 256 * 1024 * 2);
  bf16* PHIWT   = (bf16*)take((size_t)256 * 64 * 2);
  bf16* PSIWT   = (bf16*)take((size_t)256 * 64 * 2);
  bf16* QKVB    = (bf16*)take((size_t)12 * EL2M * 2);
  bf16* BIG     = (bf16*)take((size_t)32 * EL1M * 2);   // scores / performer / sub1-f32
  bf16* VT      = (bf16*)take((size_t)32 * 64 * 1024 * 2);
  bf16* MERGED  = (bf16*)take((size_t)EL2M * 2);
  bf16* CONCAT  = (bf16*)take((size_t)2048 * 2048 * 2);
  bf16* EO      = (bf16*)take((size_t)4 * EL2M * 2);
  float* F32TMP = (float*)take((size_t)EL2M * 4);       // also [4][2048][256] f32
  bf16* T1      = (bf16*)take((size_t)EL2M * 2);
  bf16* H1      = (bf16*)take((size_t)2048 * 512 * 2);
  bf16* H2      = (bf16*)take((size_t)4 * 2048 * 256 * 2);
  float* PROBS1 = (float*)take((size_t)2048 * 4 * 4);
  float* PROBS2 = (float*)take((size_t)4 * 2048 * 2 * 4);
  float* TOKIMP = (float*)take((size_t)2048 * 4);
  int*   TOPIDX = (int*)take((size_t)2 * 16 * 4);
  float* VSUMO  = (float*)take((size_t)32 * 64 * 4);
  float* KSUM   = (float*)take((size_t)32 * 256 * 4);
  float* DEN    = (float*)take((size_t)32 * 1024 * 4);

  // performer aliases inside BIG (free until expert-2 scores)
  bf16* QPHI  = BIG;                      // [32][1024][256]
  bf16* KPSI  = BIG + (size_t)8388608;    // [32][1024][256]
  bf16* KPSIT = BIG + (size_t)16777216;   // [32][256][1024]
  bf16* KVT   = BIG + (size_t)25165824;   // [32][64][256]
  float* BIGF = (float*)BIG;              // sub1 staging [2][2048][1024] f32

  // ---- phase 0: convert / transpose weights, convert x ----
  f2b_k<<<8192, 256, 0, stream>>>(x, XB, EL2M);
  transpose_conv_k<<<dim3(32, 32, 16), 256, 0, stream>>>(w_qkvo, WQKVOT, 1024, 1024);
  transpose_conv_k<<<dim3(32, 32, 8), 256, 0, stream>>>(sub_w1, SUBW1T, 1024, 1024);
  transpose_conv_k<<<dim3(32, 32, 8), 256, 0, stream>>>(sub_w2, SUBW2T, 1024, 1024);
  transpose_conv_k<<<dim3(32, 32, 1), 256, 0, stream>>>(conv_pw, CONVPWT, 1024, 1024);
  transpose_conv_k<<<dim3(32, 64, 1), 256, 0, stream>>>(fus_w, FUSWT, 2048, 1024);
  transpose_conv_k<<<dim3(16, 32, 1), 256, 0, stream>>>(r1_w1, R1W1T, 1024, 512);
  transpose_conv_k<<<dim3(8, 32, 4), 256, 0, stream>>>(r2_w1, R2W1T, 1024, 256);
  transpose_conv_k<<<dim3(8, 2, 1), 256, 0, stream>>>(phi_w, PHIWT, 64, 256);
  transpose_conv_k<<<dim3(8, 2, 1), 256, 0, stream>>>(psi_w, PSIWT, 64, 256);

  // ---- QKV projections for all 4 experts in one batched GEMM ----
  {
    GemmP g{};
    g.A = XB; g.lda = 1024;
    g.B = WQKVOT; g.ldb = 1024; g.sB0 = EL1M; g.sB1 = 4 * EL1M;
    g.C = QKVB; g.ldc = 1024; g.sC0 = EL2M; g.sC1 = 3 * EL2M;
    g.bias = b_qkvo; g.sb0 = 1024; g.sb1 = 4096;
    g.K = 1024; g.inner = 3; g.mode = 0;
    launch_gemm(stream, 0, 2048, 1024, 12, g);
  }

  // ---- expert 0: dynamic sparse attention (top-k mask shortcut) ----
  tokimp_k<<<512, 256, 0, stream>>>(x, sp_w, sp_b, TOKIMP);
  topk_k<<<2, 256, 0, stream>>>(TOKIMP, TOPIDX);
  vsum_k<<<32, 256, 0, stream>>>(QKVB + 2 * EL2M, VSUMO);
  sparse_attn_k<<<dim3(256, 32), 256, 0, stream>>>(QKVB, QKVB + EL2M, QKVB + 2 * EL2M,
                                                   VSUMO, TOPIDX, MERGED);
  {
    GemmP g{};
    g.A = MERGED; g.lda = 1024;
    g.B = WQKVOT + 3 * EL1M; g.ldb = 1024;
    g.C = EO; g.ldc = 1024;
    g.bias = b_qkvo + 3 * 1024; g.K = 1024; g.mode = 0;
    launch_gemm(stream, 0, 2048, 1024, 1, g);
  }

  // ---- expert 1: performer linear attention ----
  {
    GemmP g{};
    g.A = QKVB + 3 * EL2M; g.lda = 1024; g.sA0 = 64; g.sA1 = EL1M;
    g.B = PHIWT; g.ldb = 64;
    g.C = QPHI; g.ldc = 256; g.sC0 = 262144; g.sC1 = 16 * 262144L;
    g.bias = phi_b; g.K = 64; g.inner = 16; g.mode = 4;
    launch_gemm(stream, 0, 1024, 256, 32, g);
  }
  {
    GemmP g{};
    g.A = QKVB + 4 * EL2M; g.lda = 1024; g.sA0 = 64; g.sA1 = EL1M;
    g.B = PSIWT; g.ldb = 64;
    g.C = KPSI; g.ldc = 256; g.sC0 = 262144; g.sC1 = 16 * 262144L;
    g.bias = psi_b; g.K = 64; g.inner = 16; g.mode = 4;
    launch_gemm(stream, 0, 1024, 256, 32, g);
  }
  transpose_bf16_k<<<dim3(8, 32, 32), 256, 0, stream>>>(KPSI, KPSIT, 1024, 256, 256, 32, 262144, 0);
  ksum_k<<<32, 256, 0, stream>>>(KPSI, KSUM);
  den_k<<<8192, 256, 0, stream>>>(QPHI, KSUM, DEN);
  transpose_bf16_k<<<dim3(2, 32, 32), 256, 0, stream>>>(QKVB + 5 * EL2M, VT, 1024, 64, 1024, 16, 64, EL1M);
  {  // kv^T[m,d] = sum_l V[l,m] Kpsi[l,d]
    GemmP g{};
    g.A = VT; g.lda = 1024; g.inner = 32; g.sA0 = 65536;
    g.B = KPSIT; g.ldb = 1024; g.sB0 = 262144;
    g.C = KVT; g.ldc = 256; g.sC0 = 16384;
    g.K = 1024; g.mode = 0;
    launch_gemm(stream, 2, 64, 256, 32, g);
  }
  {  // num = qphi @ kv, fused /den, write merged
    GemmP g{};
    g.A = QPHI; g.lda = 256; g.inner = 16; g.sA0 = 262144; g.sA1 = 16 * 262144L;
    g.B = KVT; g.ldb = 256; g.sB0 = 16384; g.sB1 = 16 * 16384L;
    g.C = MERGED; g.ldc = 1024; g.sC0 = 64; g.sC1 = EL1M;
    g.rowvec = DEN; g.sRV0 = 1024; g.K = 256; g.mode = 5;
    launch_gemm(stream, 1, 1024, 64, 32, g);
  }
  {
    GemmP g{};
    g.A = MERGED; g.lda = 1024;
    g.B = WQKVOT + 7 * EL1M; g.ldb = 1024;
    g.C = EO + EL2M; g.ldc = 1024;
    g.bias = b_qkvo + 7 * 1024; g.K = 1024; g.mode = 0;
    launch_gemm(stream, 0, 2048, 1024, 1, g);
  }

  // ---- experts 2 & 3: standard softmax attention ----
  for (int e = 2; e <= 3; ++e) {
    const bf16* q = QKVB + (size_t)(e * 3 + 0) * EL2M;
    const bf16* k = QKVB + (size_t)(e * 3 + 1) * EL2M;
    const bf16* v = QKVB + (size_t)(e * 3 + 2) * EL2M;
    {  // scores = q k^T * scale
      GemmP g{};
      g.A = q; g.lda = 1024; g.inner = 16; g.sA0 = 64; g.sA1 = EL1M;
      g.B = k; g.ldb = 1024; g.sB0 = 64; g.sB1 = EL1M;
      g.C = BIG; g.ldc = 1024; g.sC0 = EL1M; g.sC1 = 16 * EL1M;
      g.K = 64; g.scale = 0.125f; g.mode = 0;
      launch_gemm(stream, 0, 1024, 1024, 32, g);
    }
    softmax_rows_k<<<32768, 256, 0, stream>>>(BIG);
    transpose_bf16_k<<<dim3(2, 32, 32), 256, 0, stream>>>(v, VT, 1024, 64, 1024, 16, 64, EL1M);
    {  // P @ V
      GemmP g{};
      g.A = BIG; g.lda = 1024; g.inner = 16; g.sA0 = EL1M; g.sA1 = 16 * EL1M;
      g.B = VT; g.ldb = 1024; g.sB0 = 65536; g.sB1 = 16 * 65536L;
      g.C = MERGED; g.ldc = 1024; g.sC0 = 64; g.sC1 = EL1M;
      g.K = 1024; g.mode = 0;
      launch_gemm(stream, 1, 1024, 64, 32, g);
    }
    if (e == 2) {
      GemmP g{};
      g.A = MERGED; g.lda = 1024;
      g.B = WQKVOT + 11 * EL1M; g.ldb = 1024;
      g.C = EO + 2 * EL2M; g.ldc = 1024;
      g.bias = b_qkvo + 11 * 1024; g.K = 1024; g.mode = 0;
      launch_gemm(stream, 0, 2048, 1024, 1, g);
    } else {  // ao -> left half of CONCAT
      GemmP g{};
      g.A = MERGED; g.lda = 1024;
      g.B = WQKVOT + 15 * EL1M; g.ldb = 1024;
      g.C = CONCAT; g.ldc = 2048;
      g.bias = b_qkvo + 15 * 1024; g.K = 1024; g.mode = 0;
      launch_gemm(stream, 0, 2048, 1024, 1, g);
    }
  }
  // conv branch -> right half of CONCAT (gelu fused)
  dwconv_k<<<8192, 256, 0, stream>>>(x, conv_dw, T1);
  {
    GemmP g{};
    g.A = T1; g.lda = 1024;
    g.B = CONVPWT; g.ldb = 1024;
    g.C = CONCAT + 1024; g.ldc = 2048;
    g.K = 1024; g.mode = 3;
    launch_gemm(stream, 0, 2048, 1024, 1, g);
  }
  {  // fusion GEMM, K=2048
    GemmP g{};
    g.A = CONCAT; g.lda = 2048;
    g.B = FUSWT; g.ldb = 2048;
    g.C = EO + 3 * EL2M; g.ldc = 1024;
    g.bias = fus_b; g.K = 2048; g.mode = 0;
    launch_gemm(stream, 0, 2048, 1024, 1, g);
  }

  // ---- routers + sub-experts ----
  (void)hipMemsetAsync(d_out, 0, (size_t)out_size * 4, stream);
  {
    GemmP g{};
    g.A = XB; g.lda = 1024;
    g.B = R1W1T; g.ldb = 1024;
    g.C = F32TMP; g.ldc = 512;
    g.bias = r1_b1; g.K = 1024; g.mode = 1;
    launch_gemm(stream, 0, 2048, 512, 1, g);
  }
  ln_act_k<<<2048, 256, 0, stream>>>(F32TMP, r1_g, r1_be, H1, 512, 0, 2048);
  router1_k<<<512, 256, 0, stream>>>(H1, r1_w2, r1_b2, PROBS1);

  {  // r2 for all 4 experts batched
    GemmP g{};
    g.A = EO; g.lda = 1024; g.sA1 = EL2M;
    g.B = R2W1T; g.ldb = 1024; g.sB1 = 262144;
    g.C = F32TMP; g.ldc = 256; g.sC1 = 2048 * 256;
    g.bias = r2_b1; g.sb1 = 256; g.K = 1024; g.mode = 1;
    launch_gemm(stream, 0, 2048, 256, 4, g);
  }
  ln_act_k<<<8192, 256, 0, stream>>>(F32TMP, r2_g, r2_be, H2, 256, 0, 2048);
  router2_k<<<2048, 256, 0, stream>>>(H2, r2_w2, r2_b2, PROBS2, 2048);

  for (int i = 0; i < 4; ++i) {
    {  // sub_w1 for both sub-experts batched
      GemmP g{};
      g.A = EO + (size_t)i * EL2M; g.lda = 1024;
      g.B = SUBW1T + (size_t)i * 2 * EL1M; g.ldb = 1024; g.sB1 = EL1M;
      g.C = BIGF; g.ldc = 1024; g.sC1 = EL2M;
      g.bias = sub_b1 + i * 2048; g.sb1 = 1024;
      g.K = 1024; g.mode = 1;
      launch_gemm(stream, 0, 2048, 1024, 2, g);
    }
    ln_act_k<<<4096, 256, 0, stream>>>(BIGF, sub_g + i * 2048, sub_be + i * 2048,
                                       (bf16*)CONCAT, 1024, 1, 2048);
    for (int j = 0; j < 2; ++j) {
      int ij = i * 2 + j;
      GemmP g{};
      g.A = (bf16*)CONCAT + (size_t)j * EL2M; g.lda = 1024;
      g.B = SUBW2T + (size_t)ij * EL1M; g.ldb = 1024;
      g.C = d_out; g.ldc = 1024;
      g.bias = sub_b2 + ij * 1024;
      g.p1 = PROBS1 + i;
      g.p2 = PROBS2 + (size_t)i * 4096 + j;
      g.K = 1024; g.mode = 2;
      launch_gemm(stream, 0, 2048, 1024, 1, g);
    }
  }
}

// Round 2
// 1233.438 us; speedup vs baseline: 1.4630x; 1.4630x over previous
//
#include <hip/hip_runtime.h>
#include <hip/hip_bf16.h>
#include <cstdint>

using bf16 = __hip_bfloat16;
typedef __attribute__((ext_vector_type(8))) short bfrag;   // 8 x bf16 (4 VGPRs)
typedef __attribute__((ext_vector_type(4))) float ffrag;   // 4 x f32 acc

#define DEV __device__ __forceinline__

DEV float wred_sum(float v) {
#pragma unroll
  for (int o = 32; o > 0; o >>= 1) v += __shfl_xor(v, o, 64);
  return v;
}
DEV float bred_sum(float v) {
  __shared__ float r[4];
  int w = threadIdx.x >> 6, l = threadIdx.x & 63;
  v = wred_sum(v);
  __syncthreads();
  if (l == 0) r[w] = v;
  __syncthreads();
  return r[0] + r[1] + r[2] + r[3];
}
DEV float bred_max(float v) {
  __shared__ float rm[4];
  int w = threadIdx.x >> 6, l = threadIdx.x & 63;
#pragma unroll
  for (int o = 32; o > 0; o >>= 1) v = fmaxf(v, __shfl_xor(v, o, 64));
  __syncthreads();
  if (l == 0) rm[w] = v;
  __syncthreads();
  return fmaxf(fmaxf(rm[0], rm[1]), fmaxf(rm[2], rm[3]));
}
DEV float gelu_f(float x) {  // jax.nn.gelu approximate=True
  float x3 = x * x * x;
  return 0.5f * x * (1.0f + tanhf(0.7978845608028654f * (x + 0.044715f * x3)));
}

// ---------------------------------------------------------------- GEMM (NT)
// C[m,n] = sum_k A[m,k] * B[n,k]
struct GemmP {
  const bf16* A; const bf16* A2; const bf16* B; void* C; void* C2;
  const float* bias; const float* rowvec;
  int K, lda, ldb, ldc, inner, mode, zBshift, c2z, kSplit;
  long sA0, sA1, sB0, sB1, sC0, sC1, sb0, sb1, sRV0;
  float scale;
};
// modes: 0 bf16 store | 1 f32 store | 3 bf16 gelu | 4 bf16 elu+1 | 5 bf16 v/rowvec[z,m]
static GemmP gp0() {
  GemmP g;
  g.A = nullptr; g.A2 = nullptr; g.B = nullptr; g.C = nullptr; g.C2 = nullptr;
  g.bias = nullptr; g.rowvec = nullptr;
  g.K = 0; g.lda = 0; g.ldb = 0; g.ldc = 0; g.inner = 1; g.mode = 0;
  g.zBshift = 0; g.c2z = -1; g.kSplit = 1 << 30;
  g.sA0 = 0; g.sA1 = 0; g.sB0 = 0; g.sB1 = 0; g.sC0 = 0; g.sC1 = 0;
  g.sb0 = 0; g.sb1 = 0; g.sRV0 = 0; g.scale = 1.f;
  return g;
}

template <int BM, int BN, int WM, int WN>
__global__ __launch_bounds__(256)
void gemm_nt(GemmP p) {
  constexpr int TI = BM / (WM * 16), TJ = BN / (WN * 16);
  __shared__ bf16 smem[(BM + BN) * 32];
  const int tid = threadIdx.x;
  const int z = blockIdx.z;
  const int z0 = z % p.inner, z1 = z / p.inner;
  const long zB = (long)(z1 >> p.zBshift);
  const bf16* A = p.A + (long)z0 * p.sA0 + (long)z1 * p.sA1;
  const bf16* Bp = p.B + (long)z0 * p.sB0 + zB * p.sB1;
  const int m0 = blockIdx.x * BM, n0 = blockIdx.y * BN;
  const int wave = tid >> 6, lane = tid & 63;
  const int wrow = wave / WN, wcol = wave % WN;
  const int fr = lane & 15, quad = lane >> 4;
  ffrag acc[TI][TJ] = {};
  constexpr int CH_A = BM * 4;
  constexpr int NIT = (BM + BN) * 4 / 256;
  for (int k0 = 0; k0 < p.K; k0 += 32) {
    const bf16* Asrc = A;
    int kc = k0;
    if (k0 >= p.kSplit) { Asrc = p.A2; kc = k0 - p.kSplit; }
#pragma unroll
    for (int it = 0; it < NIT; ++it) {
      int idx = it * 256 + tid;
      const bf16* g;
      if (idx < CH_A) {
        int r = idx >> 2, c = idx & 3;
        g = Asrc + (long)(m0 + r) * p.lda + kc + c * 8;
      } else {
        int j = idx - CH_A;
        int r = j >> 2, c = j & 3;
        g = Bp + (long)(n0 + r) * p.ldb + k0 + c * 8;
      }
      __builtin_amdgcn_global_load_lds(
          (const __attribute__((address_space(1))) void*)g,
          (__attribute__((address_space(3))) void*)(smem + idx * 8), 16, 0, 0);
    }
    __syncthreads();
    bfrag af[TI], bfb[TJ];
#pragma unroll
    for (int t = 0; t < TI; ++t)
      af[t] = *(const bfrag*)(smem + ((wrow * (TI * 16) + t * 16 + fr) * 32 + quad * 8));
#pragma unroll
    for (int t = 0; t < TJ; ++t)
      bfb[t] = *(const bfrag*)(smem + (BM * 32 + (wcol * (TJ * 16) + t * 16 + fr) * 32 + quad * 8));
#pragma unroll
    for (int ti = 0; ti < TI; ++ti)
#pragma unroll
      for (int tj = 0; tj < TJ; ++tj)
        acc[ti][tj] = __builtin_amdgcn_mfma_f32_16x16x32_bf16(af[ti], bfb[tj], acc[ti][tj], 0, 0, 0);
    __syncthreads();
  }
  const int mbase = m0 + wrow * (TI * 16), nbase = n0 + wcol * (TJ * 16);
  void* Cb = p.C;
  long zc = (long)z0 * p.sC0 + (long)z1 * p.sC1;
  if (z == p.c2z) { Cb = p.C2; zc = 0; }
  const long zb = (long)z0 * p.sb0 + zB * p.sb1;
#pragma unroll
  for (int ti = 0; ti < TI; ++ti) {
#pragma unroll
    for (int tj = 0; tj < TJ; ++tj) {
#pragma unroll
      for (int r = 0; r < 4; ++r) {
        int m = mbase + ti * 16 + quad * 4 + r;
        int n = nbase + tj * 16 + fr;
        float v = acc[ti][tj][r] * p.scale;
        if (p.bias) v += p.bias[zb + n];
        long ci = zc + (long)m * p.ldc + n;
        if (p.mode == 0) ((bf16*)Cb)[ci] = __float2bfloat16(v);
        else if (p.mode == 1) ((float*)Cb)[ci] = v;
        else if (p.mode == 3) ((bf16*)Cb)[ci] = __float2bfloat16(gelu_f(v));
        else if (p.mode == 4) ((bf16*)Cb)[ci] = __float2bfloat16(v > 0.f ? v + 1.f : __expf(v));
        else {
          float d = p.rowvec[(long)z * p.sRV0 + m];
          ((bf16*)Cb)[ci] = __float2bfloat16(v / d);
        }
      }
    }
  }
}

// cfg 0: 128x128 (wave 64x64); cfg 1: 128x64 (wave 64x32)
static void launch_gemm(hipStream_t st, int cfg, int M, int N, int batch, const GemmP& g) {
  dim3 bs(256);
  if (cfg == 0) gemm_nt<128, 128, 2, 2><<<dim3(M / 128, N / 128, batch), bs, 0, st>>>(g);
  else          gemm_nt<128, 64, 2, 2><<<dim3(M / 128, N / 64, batch), bs, 0, st>>>(g);
}

// ---------------------------------------------------------------- utility kernels
__global__ void f2b_k(const float* in, bf16* outp, long n) {
  long i = (long)blockIdx.x * 256 + threadIdx.x;
  if (i < n) outp[i] = __float2bfloat16(in[i]);
}

// 33 x (1024x1024) fp32 -> bf16 transposed, packed at outp + z*1M
__global__ void transpose_w_k(const float* w_qkvo, const float* sub_w1, const float* sub_w2,
                              const float* conv_pw, bf16* outp) {
  __shared__ float t[32][33];
  int z = blockIdx.z;
  const float* src = z < 16 ? w_qkvo + (long)z * 1048576
                   : z < 24 ? sub_w1 + (long)(z - 16) * 1048576
                   : z < 32 ? sub_w2 + (long)(z - 24) * 1048576
                            : conv_pw;
  bf16* dst = outp + (long)z * 1048576;
  int c0 = blockIdx.x * 32, r0 = blockIdx.y * 32;
  int tx = threadIdx.x & 31, ty = threadIdx.x >> 5;
#pragma unroll
  for (int i = 0; i < 32; i += 8)
    t[ty + i][tx] = src[(long)(r0 + ty + i) * 1024 + c0 + tx];
  __syncthreads();
#pragma unroll
  for (int i = 0; i < 32; i += 8)
    dst[(long)(c0 + ty + i) * 1024 + r0 + tx] = __float2bfloat16(t[tx][ty + i]);
}

// fp32 [z][R][C] -> bf16 [z][C][R]
__global__ void transpose_conv_k(const float* in, bf16* outp, int R, int C) {
  __shared__ float t[32][33];
  long zo = (long)blockIdx.z * R * C;
  int c0 = blockIdx.x * 32, r0 = blockIdx.y * 32;
  int tx = threadIdx.x & 31, ty = threadIdx.x >> 5;
#pragma unroll
  for (int i = 0; i < 32; i += 8)
    t[ty + i][tx] = in[zo + (long)(r0 + ty + i) * C + c0 + tx];
  __syncthreads();
#pragma unroll
  for (int i = 0; i < 32; i += 8)
    outp[zo + (long)(c0 + ty + i) * R + r0 + tx] = __float2bfloat16(t[tx][ty + i]);
}

// bf16 strided [z](R x C, row stride rs) -> bf16 out + z*ldz, out[c*R + r]
// z = z0 + inner*(z1 + inner2*z2), input offset z0*is0 + z1*is1 + z2*is2
__global__ void transpose_bf16_k(const bf16* in, bf16* outp, int R, int C, int rs,
                                 int inner, int inner2, long is0, long is1, long is2,
                                 long ldz) {
  __shared__ bf16 t[32][33];
  int z = blockIdx.z;
  int z0 = z % inner; int zr = z / inner;
  int z1 = zr % inner2; int z2 = zr / inner2;
  long zo = (long)z0 * is0 + (long)z1 * is1 + (long)z2 * is2;
  int c0 = blockIdx.x * 32, r0 = blockIdx.y * 32;
  int tx = threadIdx.x & 31, ty = threadIdx.x >> 5;
#pragma unroll
  for (int i = 0; i < 32; i += 8)
    t[ty + i][tx] = in[zo + (long)(r0 + ty + i) * rs + c0 + tx];
  __syncthreads();
  long ob = (long)z * ldz;
#pragma unroll
  for (int i = 0; i < 32; i += 8)
    outp[ob + (long)(c0 + ty + i) * R + r0 + tx] = t[tx][ty + i];
}

__global__ void ones_k(bf16* vtp) {  // row 64 of 32 slices [128][1024]
  int i = blockIdx.x * 256 + threadIdx.x;
  int z = i >> 10, c = i & 1023;
  vtp[(long)z * 131072 + 65536 + c] = __float2bfloat16(1.0f);
}

__global__ void biascopy_k(const float* a, const float* b, float* o) {
  int i = blockIdx.x * 256 + threadIdx.x;
  if (i < 256) o[i] = a[i];
  else if (i < 512) o[i] = b[i - 256];
}

__global__ void softmax_rows_k(bf16* sc) {  // N = 1024, in-place
  long row = blockIdx.x;
  bf16* p = sc + row * 1024;
  int tid = threadIdx.x;
  float v[4];
  float lm = -1e30f;
#pragma unroll
  for (int i = 0; i < 4; ++i) { v[i] = __bfloat162float(p[tid + i * 256]); lm = fmaxf(lm, v[i]); }
  float m = bred_max(lm);
  float ls = 0.f;
#pragma unroll
  for (int i = 0; i < 4; ++i) { v[i] = __expf(v[i] - m); ls += v[i]; }
  float inv = 1.0f / bred_sum(ls);
#pragma unroll
  for (int i = 0; i < 4; ++i) p[tid + i * 256] = __float2bfloat16(v[i] * inv);
}

// LN + act, single global read (register cache), N <= 1024
__global__ void ln_act_k(const void* in, const float* gamma, const float* beta,
                         bf16* outp, int N, int act, int rows_per_seg, int in_bf16) {
  long row = blockIdx.x;
  int tid = threadIdx.x;
  const bf16* ib = (const bf16*)in;
  const float* iff = (const float*)in;
  float vc[4];
  float ls = 0.f;
  int i = 0;
  for (int c = tid; c < N; c += 256, ++i) {
    float v = in_bf16 ? __bfloat162float(ib[row * N + c]) : iff[row * N + c];
    vc[i] = v; ls += v;
  }
  float mean = bred_sum(ls) / N;
  float lv = 0.f;
  i = 0;
  for (int c = tid; c < N; c += 256, ++i) { float d = vc[i] - mean; lv += d * d; }
  float rstd = rsqrtf(bred_sum(lv) / N + 1e-5f);
  long go = (row / rows_per_seg) * (long)N;
  const float* gp = gamma + go;
  const float* bp = beta + go;
  i = 0;
  for (int c = tid; c < N; c += 256, ++i) {
    float v = (vc[i] - mean) * rstd * gp[c] + bp[c];
    v = act ? gelu_f(v) : fmaxf(v, 0.f);
    outp[row * N + c] = __float2bfloat16(v);
  }
}

__global__ void tokimp_k(const float* x, const float* spw, const float* spb, float* outp) {
  int row = blockIdx.x * 4 + (threadIdx.x >> 6);
  int l = threadIdx.x & 63;
  const float* xp = x + (long)row * 1024;
  float a = 0.f;
  for (int c = l; c < 1024; c += 64) a += xp[c] * spw[c];
  a = wred_sum(a);
  if (l == 0) outp[row] = a + spb[0];
}

__global__ void topk_k(const float* timp, int* outp) {
  __shared__ float vals[1024];
  __shared__ float wv[4];
  __shared__ int wi[4];
  int b = blockIdx.x, tid = threadIdx.x;
  for (int c = tid; c < 1024; c += 256) vals[c] = timp[b * 1024 + c];
  __syncthreads();
  for (int t = 0; t < 10; ++t) {
    float bv = -3.0e38f; int bi = 1 << 30;
    for (int c = tid; c < 1024; c += 256) {
      float v = vals[c];
      if (v > bv || (v == bv && c < bi)) { bv = v; bi = c; }
    }
#pragma unroll
    for (int o = 32; o > 0; o >>= 1) {
      float ov = __shfl_xor(bv, o, 64); int oi = __shfl_xor(bi, o, 64);
      if (ov > bv || (ov == bv && oi < bi)) { bv = ov; bi = oi; }
    }
    int w = tid >> 6, l = tid & 63;
    if (l == 0) { wv[w] = bv; wi[w] = bi; }
    __syncthreads();
    if (tid == 0) {
      float fv = wv[0]; int fi = wi[0];
      for (int ww = 1; ww < 4; ++ww)
        if (wv[ww] > fv || (wv[ww] == fv && wi[ww] < fi)) { fv = wv[ww]; fi = wi[ww]; }
      outp[b * 16 + t] = fi;
      vals[fi] = -3.0e38f;
    }
    __syncthreads();
  }
}

// stage-1 V column sums: 512 blocks, partials [32][16][64]
__global__ void vsum_k(const bf16* v, float* vsump) {
  __shared__ float red[4][64];
  int zz = blockIdx.x;
  int z = zz >> 4, slab = zz & 15;
  int b = z >> 4, h = z & 15;
  const bf16* vp = v + (long)b * 1048576 + h * 64;
  int d = threadIdx.x & 63, sg = threadIdx.x >> 6;
  float s = 0.f;
#pragma unroll
  for (int i = 0; i < 16; ++i) {
    int srow = slab * 64 + sg * 16 + i;
    s += __bfloat162float(vp[(long)srow * 1024 + d]);
  }
  red[sg][d] = s;
  __syncthreads();
  if (sg == 0) vsump[(long)zz * 64 + d] = red[0][d] + red[1][d] + red[2][d] + red[3][d];
}

// expert-0 sparse attention, algebraically reduced
__global__ void sparse_attn_k(const bf16* q, const bf16* k, const bf16* v,
                              const float* vsump, const int* topidx, bf16* merged) {
  __shared__ float kt[10][64], vt[10][64], vs[64], vts[64];
  int z = blockIdx.y, b = z >> 4, h = z & 15;
  int tid = threadIdx.x;
  const int* tix = topidx + b * 16;
  for (int t = tid; t < 640; t += 256) {
    int tt = t >> 6, d = t & 63;
    long src = ((long)b * 1024 + tix[tt]) * 1024 + h * 64 + d;
    kt[tt][d] = __bfloat162float(k[src]);
    vt[tt][d] = __bfloat162float(v[src]);
  }
  if (tid < 64) {
    float s = 0.f;
#pragma unroll
    for (int p = 0; p < 16; ++p) s += vsump[((long)z * 16 + p) * 64 + tid];
    vs[tid] = s;
  }
  __syncthreads();
  if (tid < 64) {
    float s = 0.f;
#pragma unroll
    for (int t = 0; t < 10; ++t) s += vt[t][tid];
    vts[tid] = s;
  }
  __syncthreads();
  int wave = tid >> 6, lane = tid & 63;
  int sq = blockIdx.x * 4 + wave;
  long qi = ((long)b * 1024 + sq) * 1024 + h * 64 + lane;
  float qd = __bfloat162float(q[qi]);
  float sc[10];
#pragma unroll
  for (int t = 0; t < 10; ++t) sc[t] = wred_sum(qd * kt[t][lane]) * 0.125f;
  float m = 0.f;
#pragma unroll
  for (int t = 0; t < 10; ++t) m = fmaxf(m, sc[t]);
  float e[10], se = 0.f;
#pragma unroll
  for (int t = 0; t < 10; ++t) { e[t] = __expf(sc[t] - m); se += e[t]; }
  float em = __expf(-m);
  float Z = 1014.f * em + se;
  float o = em * (vs[lane] - vts[lane]);
#pragma unroll
  for (int t = 0; t < 10; ++t) o += e[t] * vt[t][lane];
  merged[qi] = __float2bfloat16(o / Z);
}

// den = qphi . ksum (+1e-8); ksum = row 64 of KVTX slices
__global__ void den_k(const bf16* qphi, const bf16* kvtx, float* den) {
  int r = blockIdx.x * 4 + (threadIdx.x >> 6);
  int l = threadIdx.x & 63;
  int z = r >> 10;
  const bf16* qp = qphi + (long)r * 256;
  const bf16* ks = kvtx + (long)z * 32768 + 16384;
  float a = 0.f;
  for (int c = l; c < 256; c += 64) a += __bfloat162float(qp[c]) * __bfloat162float(ks[c]);
  a = wred_sum(a);
  if (l == 0) den[r] = a + 1e-8f;
}

__global__ void dwconv_k(const float* x, const float* dw, bf16* outp) {
  long i = (long)blockIdx.x * 256 + threadIdx.x;
  int d = (int)(i & 1023);
  long row = i >> 10;
  int s = (int)(row & 1023);
  float a = x[i] * dw[1024 + d];
  if (s > 0) a += x[i - 1024] * dw[d];
  if (s < 1023) a += x[i + 1024] * dw[2048 + d];
  outp[i] = __float2bfloat16(a);
}

__global__ void router1_k(const bf16* h1, const float* w, const float* bias, float* outp) {
  int row = blockIdx.x * 4 + (threadIdx.x >> 6);
  int l = threadIdx.x & 63;
  const bf16* hp = h1 + (long)row * 512;
  float a0 = 0, a1 = 0, a2 = 0, a3 = 0;
  for (int c = l; c < 512; c += 64) {
    float hv = __bfloat162float(hp[c]);
    const float* wp = w + c * 4;
    a0 += hv * wp[0]; a1 += hv * wp[1]; a2 += hv * wp[2]; a3 += hv * wp[3];
  }
  a0 = wred_sum(a0); a1 = wred_sum(a1); a2 = wred_sum(a2); a3 = wred_sum(a3);
  a0 += bias[0]; a1 += bias[1]; a2 += bias[2]; a3 += bias[3];
  float m = fmaxf(fmaxf(a0, a1), fmaxf(a2, a3));
  float e0 = __expf(a0 - m), e1 = __expf(a1 - m), e2 = __expf(a2 - m), e3 = __expf(a3 - m);
  float inv = 1.f / (e0 + e1 + e2 + e3);
  if (l == 0) {
    float* op = outp + (long)row * 4;
    op[0] = e0 * inv; op[1] = e1 * inv; op[2] = e2 * inv; op[3] = e3 * inv;
  }
}

__global__ void router2_k(const bf16* h2, const float* w, const float* bias, float* outp,
                          int rows_per_seg) {
  int row = blockIdx.x * 4 + (threadIdx.x >> 6);
  int l = threadIdx.x & 63;
  int seg = row / rows_per_seg;
  const float* wp = w + (long)seg * 512;
  const float* bp = bias + (long)seg * 2;
  const bf16* hp = h2 + (long)row * 256;
  float a0 = 0, a1 = 0;
  for (int c = l; c < 256; c += 64) {
    float hv = __bfloat162float(hp[c]);
    a0 += hv * wp[c * 2]; a1 += hv * wp[c * 2 + 1];
  }
  a0 = wred_sum(a0); a1 = wred_sum(a1);
  a0 += bp[0]; a1 += bp[1];
  float m = fmaxf(a0, a1);
  float e0 = __expf(a0 - m), e1 = __expf(a1 - m);
  float inv = 1.f / (e0 + e1);
  if (l == 0) { outp[(long)row * 2] = e0 * inv; outp[(long)row * 2 + 1] = e1 * inv; }
}

// final: out[m,n] = sum_z p1[m][z/2] * p2[z/2][m][z&1] * part[z][m][n]
__global__ void combine_k(const bf16* part, const float* p1, const float* p2, float* outp) {
  long i = (long)blockIdx.x * 256 + threadIdx.x;
  long m = i >> 10;
  float acc = 0.f;
#pragma unroll
  for (int zz = 0; zz < 8; ++zz) {
    int e = zz >> 1, j = zz & 1;
    float w = p1[m * 4 + e] * p2[(long)e * 4096 + m * 2 + j];
    acc += w * __bfloat162float(part[(long)zz * 2097152 + i]);
  }
  outp[i] = acc;
}

// ---------------------------------------------------------------- host
extern "C" void kernel_launch(void* const* d_in, const int* in_sizes, int n_in,
                              void* d_out, int out_size, void* d_ws, size_t ws_size,
                              hipStream_t stream) {
  const float* x = (const float*)d_in[0];
  const float* w_qkvo = (const float*)d_in[1];
  const float* b_qkvo = (const float*)d_in[2];
  const float* sp_w = (const float*)d_in[3];
  const float* sp_b = (const float*)d_in[4];
  const float* phi_w = (const float*)d_in[5];
  const float* phi_b = (const float*)d_in[6];
  const float* psi_w = (const float*)d_in[7];
  const float* psi_b = (const float*)d_in[8];
  const float* conv_dw = (const float*)d_in[9];
  const float* conv_pw = (const float*)d_in[10];
  const float* fus_w = (const float*)d_in[11];
  const float* fus_b = (const float*)d_in[12];
  const float* sub_w1 = (const float*)d_in[13];
  const float* sub_b1 = (const float*)d_in[14];
  const float* sub_g = (const float*)d_in[15];
  const float* sub_be = (const float*)d_in[16];
  const float* sub_w2 = (const float*)d_in[17];
  const float* sub_b2 = (const float*)d_in[18];
  const float* r1_w1 = (const float*)d_in[19];
  const float* r1_b1 = (const float*)d_in[20];
  const float* r1_g = (const float*)d_in[21];
  const float* r1_be = (const float*)d_in[22];
  const float* r1_w2 = (const float*)d_in[23];
  const float* r1_b2 = (const float*)d_in[24];
  const float* r2_w1 = (const float*)d_in[25];
  const float* r2_b1 = (const float*)d_in[26];
  const float* r2_g = (const float*)d_in[27];
  const float* r2_be = (const float*)d_in[28];
  const float* r2_w2 = (const float*)d_in[29];
  const float* r2_b2 = (const float*)d_in[30];
  (void)in_sizes; (void)n_in; (void)ws_size; (void)out_size;

  char* ws = (char*)d_ws;
  size_t off = 0;
  auto take = [&](size_t bytes) { void* p = ws + off; off += (bytes + 255) & ~(size_t)255; return p; };

  const long EL2M = 2097152;  // 2048*1024
  const long EL1M = 1048576;  // 1024*1024

  bf16* XB      = (bf16*)take((size_t)EL2M * 2);
  bf16* WQKVOT  = (bf16*)take((size_t)16 * EL1M * 2);  // + SUBW1T/SUBW2T/CONVPWT adjacent
  bf16* SUBW1T  = (bf16*)take((size_t)8 * EL1M * 2);
  bf16* SUBW2T  = (bf16*)take((size_t)8 * EL1M * 2);
  bf16* CONVPWT = (bf16*)take((size_t)EL1M * 2);
  bf16* FUSWT   = (bf16*)take((size_t)EL2M * 2);
  bf16* R1W1T   = (bf16*)take((size_t)512 * 1024 * 2);
  bf16* R2W1T   = (bf16*)take((size_t)4 * 256 * 1024 * 2);
  bf16* PHIWT   = (bf16*)take((size_t)16384 * 2);      // PSIWT adjacent (stride 16384)
  bf16* PSIWT   = (bf16*)take((size_t)16384 * 2);
  float* PHIPSIB = (float*)take((size_t)512 * 4);
  bf16* QKVB    = (bf16*)take((size_t)12 * EL2M * 2);  // + MERGED4 adjacent -> sub arena
  bf16* MERGED4 = (bf16*)take((size_t)4 * EL2M * 2);
  bf16* VTP1    = (bf16*)take((size_t)32 * 128 * 1024 * 2);
  bf16* VT23    = (bf16*)take((size_t)64 * 64 * 1024 * 2);
  bf16* EO      = (bf16*)take((size_t)4 * EL2M * 2);
  bf16* ARENA   = (bf16*)take((size_t)64 * 1024 * 1024);
  float* PROBS1 = (float*)take((size_t)2048 * 4 * 4);
  float* PROBS2 = (float*)take((size_t)4 * 2048 * 2 * 4);
  float* TOKIMP = (float*)take((size_t)2048 * 4);
  int*   TOPIDX = (int*)take((size_t)2 * 16 * 4);
  float* VSUMP  = (float*)take((size_t)32 * 16 * 64 * 4);

  // ARENA phase 1 (performer):
  bf16* QPHI  = ARENA;                       // [32][1024][256]
  bf16* KPSI  = ARENA + 8388608;             // [32][1024][256]
  bf16* KPSIT = ARENA + 16777216;            // [32][256][1024]
  bf16* KVTX  = ARENA + 25165824;            // [32][128][256] (row64 = ksum)
  float* DEN  = (float*)(ARENA + 26214400);  // [32][1024]
  // ARENA phase 2 (attention): SC = full 64 MB
  bf16* SC = ARENA;                          // [32][1024][1024]
  // ARENA phase 3 (late):
  bf16* SUB2F = ARENA;                       // [8][2048][1024] bf16 partials
  float* F32TMP = (float*)(ARENA + 16777216);  // 8 MB
  bf16* H1 = ARENA + 20971520;               // [2048][512]
  bf16* H2 = ARENA + 22020096;               // [4*2048][256]
  bf16* AO = ARENA + 24117248;               // [2048][1024]
  bf16* XC = ARENA + 26214400;               // [2048][1024]
  bf16* T1 = ARENA + 28311552;               // [2048][1024]
  // sub arena (aliases QKVB+MERGED4, dead by then):
  bf16* SUB1A = QKVB;                        // [8][2048][1024]
  bf16* SUB1B = QKVB + 16777216;             // [8][2048][1024]

  // ---- phase 0: weights ----
  f2b_k<<<8192, 256, 0, stream>>>(x, XB, EL2M);
  transpose_w_k<<<dim3(32, 32, 33), 256, 0, stream>>>(w_qkvo, sub_w1, sub_w2, conv_pw, WQKVOT);
  transpose_conv_k<<<dim3(32, 64, 1), 256, 0, stream>>>(fus_w, FUSWT, 2048, 1024);
  transpose_conv_k<<<dim3(16, 32, 1), 256, 0, stream>>>(r1_w1, R1W1T, 1024, 512);
  transpose_conv_k<<<dim3(8, 32, 4), 256, 0, stream>>>(r2_w1, R2W1T, 1024, 256);
  transpose_conv_k<<<dim3(8, 2, 1), 256, 0, stream>>>(phi_w, PHIWT, 64, 256);
  transpose_conv_k<<<dim3(8, 2, 1), 256, 0, stream>>>(psi_w, PSIWT, 64, 256);
  biascopy_k<<<2, 256, 0, stream>>>(phi_b, psi_b, PHIPSIB);

  // ---- QKV for all experts, one batch-12 GEMM ----
  {
    GemmP g = gp0();
    g.A = XB; g.lda = 1024;
    g.B = WQKVOT; g.ldb = 1024; g.sB0 = EL1M; g.sB1 = 4 * EL1M;
    g.C = QKVB; g.ldc = 1024; g.sC0 = EL2M; g.sC1 = 3 * EL2M;
    g.bias = b_qkvo; g.sb0 = 1024; g.sb1 = 4096;
    g.K = 1024; g.inner = 3; g.mode = 0;
    launch_gemm(stream, 0, 2048, 1024, 12, g);
  }

  // ---- expert 0: sparse attention ----
  tokimp_k<<<512, 256, 0, stream>>>(x, sp_w, sp_b, TOKIMP);
  topk_k<<<2, 256, 0, stream>>>(TOKIMP, TOPIDX);
  vsum_k<<<512, 256, 0, stream>>>(QKVB + 2 * EL2M, VSUMP);
  sparse_attn_k<<<dim3(256, 32), 256, 0, stream>>>(QKVB, QKVB + EL2M, QKVB + 2 * EL2M,
                                                   VSUMP, TOPIDX, MERGED4);

  // ---- expert 1: performer ----
  {  // phi(Q) and psi(K) in one batch-64 GEMM (z1 = b + 2*pp)
    GemmP g = gp0();
    g.A = QKVB + 3 * EL2M; g.lda = 1024; g.sA0 = 64; g.sA1 = EL1M;
    g.B = PHIWT; g.ldb = 64; g.sB1 = 16384; g.zBshift = 1;
    g.C = QPHI; g.ldc = 256; g.sC0 = 262144; g.sC1 = 16 * 262144L;
    g.bias = PHIPSIB; g.sb1 = 256;
    g.K = 64; g.inner = 16; g.mode = 4;
    launch_gemm(stream, 0, 1024, 256, 64, g);
  }
  transpose_bf16_k<<<dim3(8, 32, 32), 256, 0, stream>>>(KPSI, KPSIT, 1024, 256, 256,
                                                        32, 1, 262144, 0, 0, 262144);
  transpose_bf16_k<<<dim3(2, 32, 32), 256, 0, stream>>>(QKVB + 5 * EL2M, VTP1, 1024, 64, 1024,
                                                        16, 2, 64, EL1M, 0, 131072);
  ones_k<<<128, 256, 0, stream>>>(VTP1);
  {  // KVTX[m,d] = sum_l VTP1[m,l]*KPSIT[d,l]; row 64 = ksum
    GemmP g = gp0();
    g.A = VTP1; g.lda = 1024; g.sA0 = 131072; g.sA1 = 16 * 131072L;
    g.B = KPSIT; g.ldb = 1024; g.sB0 = 262144; g.sB1 = 16 * 262144L;
    g.C = KVTX; g.ldc = 256; g.sC0 = 32768; g.sC1 = 16 * 32768L;
    g.K = 1024; g.inner = 16; g.mode = 0;
    launch_gemm(stream, 1, 128, 256, 32, g);
  }
  den_k<<<8192, 256, 0, stream>>>(QPHI, KVTX, DEN);
  {  // num = qphi @ kv / den -> merged slice 1
    GemmP g = gp0();
    g.A = QPHI; g.lda = 256; g.sA0 = 262144; g.sA1 = 16 * 262144L;
    g.B = KVTX; g.ldb = 256; g.sB0 = 32768; g.sB1 = 16 * 32768L;
    g.C = MERGED4 + EL2M; g.ldc = 1024; g.sC0 = 64; g.sC1 = EL1M;
    g.rowvec = DEN; g.sRV0 = 1024;
    g.K = 256; g.inner = 16; g.mode = 5;
    launch_gemm(stream, 1, 1024, 64, 32, g);
  }

  // ---- V^T for experts 2,3 (batch 64) ----
  transpose_bf16_k<<<dim3(2, 32, 64), 256, 0, stream>>>(QKVB + 8 * EL2M, VT23, 1024, 64, 1024,
                                                        16, 2, 64, EL1M, 3 * EL2M, 65536);

  // ---- experts 2 & 3: softmax attention ----
  for (int e = 2; e <= 3; ++e) {
    const bf16* q = QKVB + (size_t)(e * 3 + 0) * EL2M;
    const bf16* k = QKVB + (size_t)(e * 3 + 1) * EL2M;
    {
      GemmP g = gp0();
      g.A = q; g.lda = 1024; g.sA0 = 64; g.sA1 = EL1M;
      g.B = k; g.ldb = 1024; g.sB0 = 64; g.sB1 = EL1M;
      g.C = SC; g.ldc = 1024; g.sC0 = EL1M; g.sC1 = 16 * EL1M;
      g.K = 64; g.inner = 16; g.scale = 0.125f; g.mode = 0;
      launch_gemm(stream, 0, 1024, 1024, 32, g);
    }
    softmax_rows_k<<<32768, 256, 0, stream>>>(SC);
    {  // P @ V -> merged slice e
      GemmP g = gp0();
      g.A = SC; g.lda = 1024; g.sA0 = EL1M; g.sA1 = 16 * EL1M;
      g.B = VT23 + (size_t)(e - 2) * 32 * 65536; g.ldb = 1024; g.sB0 = 65536; g.sB1 = 16 * 65536L;
      g.C = MERGED4 + (size_t)e * EL2M; g.ldc = 1024; g.sC0 = 64; g.sC1 = EL1M;
      g.K = 1024; g.inner = 16; g.mode = 0;
      launch_gemm(stream, 1, 1024, 64, 32, g);
    }
  }

  // ---- batch-4 output projection (z=3 -> AO) ----
  {
    GemmP g = gp0();
    g.A = MERGED4; g.lda = 1024; g.sA1 = EL2M;
    g.B = WQKVOT + 3 * EL1M; g.ldb = 1024; g.sB1 = 4 * EL1M;
    g.C = EO; g.ldc = 1024; g.sC1 = EL2M;
    g.C2 = AO; g.c2z = 3;
    g.bias = b_qkvo + 3 * 1024; g.sb1 = 4096;
    g.K = 1024; g.mode = 0;
    launch_gemm(stream, 0, 2048, 1024, 4, g);
  }

  // ---- conv branch + fusion ----
  dwconv_k<<<8192, 256, 0, stream>>>(x, conv_dw, T1);
  {
    GemmP g = gp0();
    g.A = T1; g.lda = 1024;
    g.B = CONVPWT; g.ldb = 1024;
    g.C = XC; g.ldc = 1024;
    g.K = 1024; g.mode = 3;
    launch_gemm(stream, 1, 2048, 1024, 1, g);
  }
  {  // fusion: A = [AO | XC], K=2048
    GemmP g = gp0();
    g.A = AO; g.A2 = XC; g.kSplit = 1024; g.lda = 1024;
    g.B = FUSWT; g.ldb = 2048;
    g.C = EO + 3 * EL2M; g.ldc = 1024;
    g.bias = fus_b; g.K = 2048; g.mode = 0;
    launch_gemm(stream, 1, 2048, 1024, 1, g);
  }

  // ---- routers ----
  {
    GemmP g = gp0();
    g.A = XB; g.lda = 1024;
    g.B = R1W1T; g.ldb = 1024;
    g.C = F32TMP; g.ldc = 512;
    g.bias = r1_b1; g.K = 1024; g.mode = 1;
    launch_gemm(stream, 1, 2048, 512, 1, g);
  }
  ln_act_k<<<2048, 256, 0, stream>>>(F32TMP, r1_g, r1_be, H1, 512, 0, 2048, 0);
  router1_k<<<512, 256, 0, stream>>>(H1, r1_w2, r1_b2, PROBS1);
  {
    GemmP g = gp0();
    g.A = EO; g.lda = 1024; g.sA1 = EL2M;
    g.B = R2W1T; g.ldb = 1024; g.sB1 = 262144;
    g.C = F32TMP; g.ldc = 256; g.sC1 = 2048 * 256;
    g.bias = r2_b1; g.sb1 = 256; g.K = 1024; g.mode = 1;
    launch_gemm(stream, 1, 2048, 256, 4, g);
  }
  ln_act_k<<<8192, 256, 0, stream>>>(F32TMP, r2_g, r2_be, H2, 256, 0, 2048, 0);
  router2_k<<<2048, 256, 0, stream>>>(H2, r2_w2, r2_b2, PROBS2, 2048);

  // ---- sub-experts: batch-8 everything ----
  {  // sub1: z = j + 2*i
    GemmP g = gp0();
    g.A = EO; g.lda = 1024; g.sA1 = EL2M;
    g.B = SUBW1T; g.ldb = 1024; g.sB0 = EL1M; g.sB1 = 2 * EL1M;
    g.C = SUB1A; g.ldc = 1024; g.sC0 = EL2M; g.sC1 = 2 * EL2M;
    g.bias = sub_b1; g.sb0 = 1024; g.sb1 = 2048;
    g.K = 1024; g.inner = 2; g.mode = 0;
    launch_gemm(stream, 0, 2048, 1024, 8, g);
  }
  ln_act_k<<<16384, 256, 0, stream>>>(SUB1A, sub_g, sub_be, SUB1B, 1024, 1, 2048, 1);
  {  // sub2 partials (bias folded)
    GemmP g = gp0();
    g.A = SUB1B; g.lda = 1024; g.sA1 = EL2M;
    g.B = SUBW2T; g.ldb = 1024; g.sB1 = EL1M;
    g.C = SUB2F; g.ldc = 1024; g.sC1 = EL2M;
    g.bias = sub_b2; g.sb1 = 1024;
    g.K = 1024; g.mode = 0;
    launch_gemm(stream, 0, 2048, 1024, 8, g);
  }
  combine_k<<<8192, 256, 0, stream>>>(SUB2F, PROBS1, PROBS2, (float*)d_out);
}

// Round 4
// 1104.832 us; speedup vs baseline: 1.6333x; 1.1164x over previous
//
#include <hip/hip_runtime.h>
#include <hip/hip_bf16.h>
#include <cstdint>

using bf16 = __hip_bfloat16;
typedef __attribute__((ext_vector_type(8))) short bfrag;   // 8 x bf16 (4 VGPRs)
typedef __attribute__((ext_vector_type(4))) float ffrag;   // 4 x f32 acc

#define DEV __device__ __forceinline__

DEV float wred_sum(float v) {
#pragma unroll
  for (int o = 32; o > 0; o >>= 1) v += __shfl_xor(v, o, 64);
  return v;
}
DEV float bred_sum(float v) {
  __shared__ float r[4];
  int w = threadIdx.x >> 6, l = threadIdx.x & 63;
  v = wred_sum(v);
  __syncthreads();
  if (l == 0) r[w] = v;
  __syncthreads();
  return r[0] + r[1] + r[2] + r[3];
}
DEV float bred_max(float v) {
  __shared__ float rm[4];
  int w = threadIdx.x >> 6, l = threadIdx.x & 63;
#pragma unroll
  for (int o = 32; o > 0; o >>= 1) v = fmaxf(v, __shfl_xor(v, o, 64));
  __syncthreads();
  if (l == 0) rm[w] = v;
  __syncthreads();
  return fmaxf(fmaxf(rm[0], rm[1]), fmaxf(rm[2], rm[3]));
}
DEV float gelu_f(float x) {  // jax.nn.gelu approximate=True
  float x3 = x * x * x;
  return 0.5f * x * (1.0f + tanhf(0.7978845608028654f * (x + 0.044715f * x3)));
}

// ---------------------------------------------------------------- GEMM (NT)
// C[m,n] = sum_k A[m,k] * B[n,k]
struct GemmP {
  const bf16* A; const bf16* A2; const bf16* B; void* C; void* C2;
  const float* bias; const float* rowvec;
  int K, lda, ldb, ldc, inner, mode, zBshift, c2z, kSplit;
  long sA0, sA1, sB0, sB1, sC0, sC1, sb0, sb1, sRV0;
  float scale;
};
// modes: 0 bf16 store | 1 f32 store | 3 bf16 gelu | 4 bf16 elu+1 | 5 bf16 v/rowvec[z,m]
static GemmP gp0() {
  GemmP g;
  g.A = nullptr; g.A2 = nullptr; g.B = nullptr; g.C = nullptr; g.C2 = nullptr;
  g.bias = nullptr; g.rowvec = nullptr;
  g.K = 0; g.lda = 0; g.ldb = 0; g.ldc = 0; g.inner = 1; g.mode = 0;
  g.zBshift = 0; g.c2z = -1; g.kSplit = 1 << 30;
  g.sA0 = 0; g.sA1 = 0; g.sB0 = 0; g.sB1 = 0; g.sC0 = 0; g.sC1 = 0;
  g.sb0 = 0; g.sb1 = 0; g.sRV0 = 0; g.scale = 1.f;
  return g;
}

// SPLIT=false keeps the K-loop branch-free; only the fusion GEMM
// (split A, K=2048) pays for the in-loop pointer switch.
template <int BM, int BN, int WM, int WN, bool SPLIT>
__global__ __launch_bounds__(256)
void gemm_nt(GemmP p) {
  constexpr int TI = BM / (WM * 16), TJ = BN / (WN * 16);
  __shared__ bf16 smem[(BM + BN) * 32];
  const int tid = threadIdx.x;
  const int z = blockIdx.z;
  const int z0 = z % p.inner, z1 = z / p.inner;
  const long zB = (long)(z1 >> p.zBshift);
  const bf16* A = p.A + (long)z0 * p.sA0 + (long)z1 * p.sA1;
  const bf16* Bp = p.B + (long)z0 * p.sB0 + zB * p.sB1;
  const int m0 = blockIdx.x * BM, n0 = blockIdx.y * BN;
  const int wave = tid >> 6, lane = tid & 63;
  const int wrow = wave / WN, wcol = wave % WN;
  const int fr = lane & 15, quad = lane >> 4;
  ffrag acc[TI][TJ] = {};
  constexpr int CH_A = BM * 4;
  constexpr int NIT = (BM + BN) * 4 / 256;
  for (int k0 = 0; k0 < p.K; k0 += 32) {
    const bf16* Asrc = A;
    int kc = k0;
    if constexpr (SPLIT) {
      if (k0 >= p.kSplit) { Asrc = p.A2; kc = k0 - p.kSplit; }
    }
#pragma unroll
    for (int it = 0; it < NIT; ++it) {
      int idx = it * 256 + tid;
      const bf16* g;
      if (idx < CH_A) {
        int r = idx >> 2, c = idx & 3;
        g = Asrc + (long)(m0 + r) * p.lda + kc + c * 8;
      } else {
        int j = idx - CH_A;
        int r = j >> 2, c = j & 3;
        g = Bp + (long)(n0 + r) * p.ldb + k0 + c * 8;
      }
      __builtin_amdgcn_global_load_lds(
          (const __attribute__((address_space(1))) void*)g,
          (__attribute__((address_space(3))) void*)(smem + idx * 8), 16, 0, 0);
    }
    __syncthreads();
    bfrag af[TI], bfb[TJ];
#pragma unroll
    for (int t = 0; t < TI; ++t)
      af[t] = *(const bfrag*)(smem + ((wrow * (TI * 16) + t * 16 + fr) * 32 + quad * 8));
#pragma unroll
    for (int t = 0; t < TJ; ++t)
      bfb[t] = *(const bfrag*)(smem + (BM * 32 + (wcol * (TJ * 16) + t * 16 + fr) * 32 + quad * 8));
#pragma unroll
    for (int ti = 0; ti < TI; ++ti)
#pragma unroll
      for (int tj = 0; tj < TJ; ++tj)
        acc[ti][tj] = __builtin_amdgcn_mfma_f32_16x16x32_bf16(af[ti], bfb[tj], acc[ti][tj], 0, 0, 0);
    __syncthreads();
  }
  const int mbase = m0 + wrow * (TI * 16), nbase = n0 + wcol * (TJ * 16);
  void* Cb = p.C;
  long zc = (long)z0 * p.sC0 + (long)z1 * p.sC1;
  if (z == p.c2z) { Cb = p.C2; zc = 0; }
  const long zb = (long)z0 * p.sb0 + zB * p.sb1;
#pragma unroll
  for (int ti = 0; ti < TI; ++ti) {
#pragma unroll
    for (int tj = 0; tj < TJ; ++tj) {
#pragma unroll
      for (int r = 0; r < 4; ++r) {
        int m = mbase + ti * 16 + quad * 4 + r;
        int n = nbase + tj * 16 + fr;
        float v = acc[ti][tj][r] * p.scale;
        if (p.bias) v += p.bias[zb + n];
        long ci = zc + (long)m * p.ldc + n;
        if (p.mode == 0) ((bf16*)Cb)[ci] = __float2bfloat16(v);
        else if (p.mode == 1) ((float*)Cb)[ci] = v;
        else if (p.mode == 3) ((bf16*)Cb)[ci] = __float2bfloat16(gelu_f(v));
        else if (p.mode == 4) ((bf16*)Cb)[ci] = __float2bfloat16(v > 0.f ? v + 1.f : __expf(v));
        else {
          float d = p.rowvec[(long)z * p.sRV0 + m];
          ((bf16*)Cb)[ci] = __float2bfloat16(v / d);
        }
      }
    }
  }
}

// cfg 0: 128x128; cfg 1: 128x64; cfg 2: 128x64 + split-A
static void launch_gemm(hipStream_t st, int cfg, int M, int N, int batch, const GemmP& g) {
  dim3 bs(256);
  if (cfg == 0)      gemm_nt<128, 128, 2, 2, false><<<dim3(M / 128, N / 128, batch), bs, 0, st>>>(g);
  else if (cfg == 1) gemm_nt<128, 64, 2, 2, false><<<dim3(M / 128, N / 64, batch), bs, 0, st>>>(g);
  else               gemm_nt<128, 64, 2, 2, true><<<dim3(M / 128, N / 64, batch), bs, 0, st>>>(g);
}

// ---------------------------------------------------------------- prep (all weight transposes)
// grid (32, 64, 42); src[R][C] f32 -> dst[C][R] bf16, demuxed on z
__global__ void prep_k(const float* w_qkvo, const float* sub_w1, const float* sub_w2,
                       const float* conv_pw, const float* fus_w, const float* r1_w1,
                       const float* r2_w1, const float* phi_w, const float* psi_w,
                       const float* phi_b, const float* psi_b,
                       bf16* wt, bf16* fuswt, bf16* r1w1t, bf16* r2w1t,
                       bf16* phiwt, bf16* psiwt, float* phipsib, bf16* vtp1) {
  int z = blockIdx.z;
  int bx = blockIdx.x, by = blockIdx.y;
  int tx = threadIdx.x & 31, ty = threadIdx.x >> 5;
  const float* src; bf16* dst; int R, C;
  if (z < 33) {
    if (by >= 32) return;
    src = z < 16 ? w_qkvo + (long)z * 1048576
        : z < 24 ? sub_w1 + (long)(z - 16) * 1048576
        : z < 32 ? sub_w2 + (long)(z - 24) * 1048576
                 : conv_pw;
    dst = wt + (long)z * 1048576; R = 1024; C = 1024;
  } else if (z == 33) {
    src = fus_w; dst = fuswt; R = 2048; C = 1024;
  } else if (z == 34) {
    if (bx >= 16 || by >= 32) return;
    src = r1_w1; dst = r1w1t; R = 1024; C = 512;
  } else if (z < 39) {
    if (bx >= 8 || by >= 32) return;
    src = r2_w1 + (long)(z - 35) * 262144; dst = r2w1t + (long)(z - 35) * 262144;
    R = 1024; C = 256;
  } else if (z < 41) {
    if (bx >= 8 || by >= 2) return;
    src = (z == 39) ? phi_w : psi_w; dst = (z == 39) ? phiwt : psiwt; R = 64; C = 256;
  } else {
    if (by == 0) {  // ones row (performer ksum trick): slice bx of VTP1
      for (int c = threadIdx.x; c < 1024; c += 256)
        vtp1[(long)bx * 131072 + 65536 + c] = __float2bfloat16(1.0f);
    } else if (by == 1 && bx == 0) {
      for (int i = threadIdx.x; i < 512; i += 256)
        phipsib[i] = i < 256 ? phi_b[i] : psi_b[i - 256];
    }
    return;
  }
  __shared__ float t[32][33];
  int c0 = bx * 32, r0 = by * 32;
#pragma unroll
  for (int i = 0; i < 32; i += 8)
    t[ty + i][tx] = src[(long)(r0 + ty + i) * C + c0 + tx];
  __syncthreads();
#pragma unroll
  for (int i = 0; i < 32; i += 8)
    dst[(long)(c0 + ty + i) * R + r0 + tx] = __float2bfloat16(t[tx][ty + i]);
}

// x -> bf16 copy + depthwise conv branch, one pass over x
__global__ void xprep_k(const float* x, const float* dw, bf16* xb, bf16* t1) {
  long i = (long)blockIdx.x * 256 + threadIdx.x;
  float xv = x[i];
  xb[i] = __float2bfloat16(xv);
  int d = (int)(i & 1023);
  long row = i >> 10;
  int s = (int)(row & 1023);
  float a = xv * dw[1024 + d];
  if (s > 0) a += x[i - 1024] * dw[d];
  if (s < 1023) a += x[i + 1024] * dw[2048 + d];
  t1[i] = __float2bfloat16(a);
}

// bf16 strided [z](R x C, row stride rs) -> bf16 out + z*ldz, out[c*R + r]
// z = z0 + inner*(z1 + inner2*z2), input offset z0*is0 + z1*is1 + z2*is2
__global__ void transpose_bf16_k(const bf16* in, bf16* outp, int R, int C, int rs,
                                 int inner, int inner2, long is0, long is1, long is2,
                                 long ldz) {
  __shared__ bf16 t[32][33];
  int z = blockIdx.z;
  int z0 = z % inner; int zr = z / inner;
  int z1 = zr % inner2; int z2 = zr / inner2;
  long zo = (long)z0 * is0 + (long)z1 * is1 + (long)z2 * is2;
  int c0 = blockIdx.x * 32, r0 = blockIdx.y * 32;
  int tx = threadIdx.x & 31, ty = threadIdx.x >> 5;
#pragma unroll
  for (int i = 0; i < 32; i += 8)
    t[ty + i][tx] = in[zo + (long)(r0 + ty + i) * rs + c0 + tx];
  __syncthreads();
  long ob = (long)z * ldz;
#pragma unroll
  for (int i = 0; i < 32; i += 8)
    outp[ob + (long)(c0 + ty + i) * R + r0 + tx] = t[tx][ty + i];
}

__global__ void softmax_rows_k(bf16* sc) {  // N = 1024, in-place
  long row = blockIdx.x;
  bf16* p = sc + row * 1024;
  int tid = threadIdx.x;
  float v[4];
  float lm = -1e30f;
#pragma unroll
  for (int i = 0; i < 4; ++i) { v[i] = __bfloat162float(p[tid + i * 256]); lm = fmaxf(lm, v[i]); }
  float m = bred_max(lm);
  float ls = 0.f;
#pragma unroll
  for (int i = 0; i < 4; ++i) { v[i] = __expf(v[i] - m); ls += v[i]; }
  float inv = 1.0f / bred_sum(ls);
#pragma unroll
  for (int i = 0; i < 4; ++i) p[tid + i * 256] = __float2bfloat16(v[i] * inv);
}

// LN + act, single global read (register cache), N <= 1024
__global__ void ln_act_k(const void* in, const float* gamma, const float* beta,
                         bf16* outp, int N, int act, int rows_per_seg, int in_bf16) {
  long row = blockIdx.x;
  int tid = threadIdx.x;
  const bf16* ib = (const bf16*)in;
  const float* iff = (const float*)in;
  float vc[4];
  float ls = 0.f;
  int i = 0;
  for (int c = tid; c < N; c += 256, ++i) {
    float v = in_bf16 ? __bfloat162float(ib[row * N + c]) : iff[row * N + c];
    vc[i] = v; ls += v;
  }
  float mean = bred_sum(ls) / N;
  float lv = 0.f;
  i = 0;
  for (int c = tid; c < N; c += 256, ++i) { float d = vc[i] - mean; lv += d * d; }
  float rstd = rsqrtf(bred_sum(lv) / N + 1e-5f);
  long go = (row / rows_per_seg) * (long)N;
  const float* gp = gamma + go;
  const float* bp = beta + go;
  i = 0;
  for (int c = tid; c < N; c += 256, ++i) {
    float v = (vc[i] - mean) * rstd * gp[c] + bp[c];
    v = act ? gelu_f(v) : fmaxf(v, 0.f);
    outp[row * N + c] = __float2bfloat16(v);
  }
}

__global__ void tokimp_k(const float* x, const float* spw, const float* spb, float* outp) {
  int row = blockIdx.x * 4 + (threadIdx.x >> 6);
  int l = threadIdx.x & 63;
  const float* xp = x + (long)row * 1024;
  float a = 0.f;
  for (int c = l; c < 1024; c += 64) a += xp[c] * spw[c];
  a = wred_sum(a);
  if (l == 0) outp[row] = a + spb[0];
}

__global__ void topk_k(const float* timp, int* outp) {
  __shared__ float vals[1024];
  __shared__ float wv[4];
  __shared__ int wi[4];
  int b = blockIdx.x, tid = threadIdx.x;
  for (int c = tid; c < 1024; c += 256) vals[c] = timp[b * 1024 + c];
  __syncthreads();
  for (int t = 0; t < 10; ++t) {
    float bv = -3.0e38f; int bi = 1 << 30;
    for (int c = tid; c < 1024; c += 256) {
      float v = vals[c];
      if (v > bv || (v == bv && c < bi)) { bv = v; bi = c; }
    }
#pragma unroll
    for (int o = 32; o > 0; o >>= 1) {
      float ov = __shfl_xor(bv, o, 64); int oi = __shfl_xor(bi, o, 64);
      if (ov > bv || (ov == bv && oi < bi)) { bv = ov; bi = oi; }
    }
    int w = tid >> 6, l = tid & 63;
    if (l == 0) { wv[w] = bv; wi[w] = bi; }
    __syncthreads();
    if (tid == 0) {
      float fv = wv[0]; int fi = wi[0];
      for (int ww = 1; ww < 4; ++ww)
        if (wv[ww] > fv || (wv[ww] == fv && wi[ww] < fi)) { fv = wv[ww]; fi = wi[ww]; }
      outp[b * 16 + t] = fi;
      vals[fi] = -3.0e38f;
    }
    __syncthreads();
  }
}

// stage-1 V column sums: 512 blocks, partials [32][16][64]
__global__ void vsum_k(const bf16* v, float* vsump) {
  __shared__ float red[4][64];
  int zz = blockIdx.x;
  int z = zz >> 4, slab = zz & 15;
  int b = z >> 4, h = z & 15;
  const bf16* vp = v + (long)b * 1048576 + h * 64;
  int d = threadIdx.x & 63, sg = threadIdx.x >> 6;
  float s = 0.f;
#pragma unroll
  for (int i = 0; i < 16; ++i) {
    int srow = slab * 64 + sg * 16 + i;
    s += __bfloat162float(vp[(long)srow * 1024 + d]);
  }
  red[sg][d] = s;
  __syncthreads();
  if (sg == 0) vsump[(long)zz * 64 + d] = red[0][d] + red[1][d] + red[2][d] + red[3][d];
}

// expert-0 sparse attention, algebraically reduced
__global__ void sparse_attn_k(const bf16* q, const bf16* k, const bf16* v,
                              const float* vsump, const int* topidx, bf16* merged) {
  __shared__ float kt[10][64], vt[10][64], vs[64], vts[64];
  int z = blockIdx.y, b = z >> 4, h = z & 15;
  int tid = threadIdx.x;
  const int* tix = topidx + b * 16;
  for (int t = tid; t < 640; t += 256) {
    int tt = t >> 6, d = t & 63;
    long src = ((long)b * 1024 + tix[tt]) * 1024 + h * 64 + d;
    kt[tt][d] = __bfloat162float(k[src]);
    vt[tt][d] = __bfloat162float(v[src]);
  }
  if (tid < 64) {
    float s = 0.f;
#pragma unroll
    for (int p = 0; p < 16; ++p) s += vsump[((long)z * 16 + p) * 64 + tid];
    vs[tid] = s;
  }
  __syncthreads();
  if (tid < 64) {
    float s = 0.f;
#pragma unroll
    for (int t = 0; t < 10; ++t) s += vt[t][tid];
    vts[tid] = s;
  }
  __syncthreads();
  int wave = tid >> 6, lane = tid & 63;
  int sq = blockIdx.x * 4 + wave;
  long qi = ((long)b * 1024 + sq) * 1024 + h * 64 + lane;
  float qd = __bfloat162float(q[qi]);
  float sc[10];
#pragma unroll
  for (int t = 0; t < 10; ++t) sc[t] = wred_sum(qd * kt[t][lane]) * 0.125f;
  float m = 0.f;
#pragma unroll
  for (int t = 0; t < 10; ++t) m = fmaxf(m, sc[t]);
  float e[10], se = 0.f;
#pragma unroll
  for (int t = 0; t < 10; ++t) { e[t] = __expf(sc[t] - m); se += e[t]; }
  float em = __expf(-m);
  float Z = 1014.f * em + se;
  float o = em * (vs[lane] - vts[lane]);
#pragma unroll
  for (int t = 0; t < 10; ++t) o += e[t] * vt[t][lane];
  merged[qi] = __float2bfloat16(o / Z);
}

// den = qphi . ksum (+1e-8); ksum = row 64 of KVTX slices
__global__ void den_k(const bf16* qphi, const bf16* kvtx, float* den) {
  int r = blockIdx.x * 4 + (threadIdx.x >> 6);
  int l = threadIdx.x & 63;
  int z = r >> 10;
  const bf16* qp = qphi + (long)r * 256;
  const bf16* ks = kvtx + (long)z * 32768 + 16384;
  float a = 0.f;
  for (int c = l; c < 256; c += 64) a += __bfloat162float(qp[c]) * __bfloat162float(ks[c]);
  a = wred_sum(a);
  if (l == 0) den[r] = a + 1e-8f;
}

__global__ void router1_k(const bf16* h1, const float* w, const float* bias, float* outp) {
  int row = blockIdx.x * 4 + (threadIdx.x >> 6);
  int l = threadIdx.x & 63;
  const bf16* hp = h1 + (long)row * 512;
  float a0 = 0, a1 = 0, a2 = 0, a3 = 0;
  for (int c = l; c < 512; c += 64) {
    float hv = __bfloat162float(hp[c]);
    const float* wp = w + c * 4;
    a0 += hv * wp[0]; a1 += hv * wp[1]; a2 += hv * wp[2]; a3 += hv * wp[3];
  }
  a0 = wred_sum(a0); a1 = wred_sum(a1); a2 = wred_sum(a2); a3 = wred_sum(a3);
  a0 += bias[0]; a1 += bias[1]; a2 += bias[2]; a3 += bias[3];
  float m = fmaxf(fmaxf(a0, a1), fmaxf(a2, a3));
  float e0 = __expf(a0 - m), e1 = __expf(a1 - m), e2 = __expf(a2 - m), e3 = __expf(a3 - m);
  float inv = 1.f / (e0 + e1 + e2 + e3);
  if (l == 0) {
    float* op = outp + (long)row * 4;
    op[0] = e0 * inv; op[1] = e1 * inv; op[2] = e2 * inv; op[3] = e3 * inv;
  }
}

__global__ void router2_k(const bf16* h2, const float* w, const float* bias, float* outp,
                          int rows_per_seg) {
  int row = blockIdx.x * 4 + (threadIdx.x >> 6);
  int l = threadIdx.x & 63;
  int seg = row / rows_per_seg;
  const float* wp = w + (long)seg * 512;
  const float* bp = bias + (long)seg * 2;
  const bf16* hp = h2 + (long)row * 256;
  float a0 = 0, a1 = 0;
  for (int c = l; c < 256; c += 64) {
    float hv = __bfloat162float(hp[c]);
    a0 += hv * wp[c * 2]; a1 += hv * wp[c * 2 + 1];
  }
  a0 = wred_sum(a0); a1 = wred_sum(a1);
  a0 += bp[0]; a1 += bp[1];
  float m = fmaxf(a0, a1);
  float e0 = __expf(a0 - m), e1 = __expf(a1 - m);
  float inv = 1.f / (e0 + e1);
  if (l == 0) { outp[(long)row * 2] = e0 * inv; outp[(long)row * 2 + 1] = e1 * inv; }
}

// final: out[m,n] = sum_z p1[m][z/2] * p2[z/2][m][z&1] * part[z][m][n]
__global__ void combine_k(const bf16* part, const float* p1, const float* p2, float* outp) {
  long i = (long)blockIdx.x * 256 + threadIdx.x;
  long m = i >> 10;
  float acc = 0.f;
#pragma unroll
  for (int zz = 0; zz < 8; ++zz) {
    int e = zz >> 1, j = zz & 1;
    float w = p1[m * 4 + e] * p2[(long)e * 4096 + m * 2 + j];
    acc += w * __bfloat162float(part[(long)zz * 2097152 + i]);
  }
  outp[i] = acc;
}

// ---------------------------------------------------------------- host
extern "C" void kernel_launch(void* const* d_in, const int* in_sizes, int n_in,
                              void* d_out, int out_size, void* d_ws, size_t ws_size,
                              hipStream_t stream) {
  const float* x = (const float*)d_in[0];
  const float* w_qkvo = (const float*)d_in[1];
  const float* b_qkvo = (const float*)d_in[2];
  const float* sp_w = (const float*)d_in[3];
  const float* sp_b = (const float*)d_in[4];
  const float* phi_w = (const float*)d_in[5];
  const float* phi_b = (const float*)d_in[6];
  const float* psi_w = (const float*)d_in[7];
  const float* psi_b = (const float*)d_in[8];
  const float* conv_dw = (const float*)d_in[9];
  const float* conv_pw = (const float*)d_in[10];
  const float* fus_w = (const float*)d_in[11];
  const float* fus_b = (const float*)d_in[12];
  const float* sub_w1 = (const float*)d_in[13];
  const float* sub_b1 = (const float*)d_in[14];
  const float* sub_g = (const float*)d_in[15];
  const float* sub_be = (const float*)d_in[16];
  const float* sub_w2 = (const float*)d_in[17];
  const float* sub_b2 = (const float*)d_in[18];
  const float* r1_w1 = (const float*)d_in[19];
  const float* r1_b1 = (const float*)d_in[20];
  const float* r1_g = (const float*)d_in[21];
  const float* r1_be = (const float*)d_in[22];
  const float* r1_w2 = (const float*)d_in[23];
  const float* r1_b2 = (const float*)d_in[24];
  const float* r2_w1 = (const float*)d_in[25];
  const float* r2_b1 = (const float*)d_in[26];
  const float* r2_g = (const float*)d_in[27];
  const float* r2_be = (const float*)d_in[28];
  const float* r2_w2 = (const float*)d_in[29];
  const float* r2_b2 = (const float*)d_in[30];
  (void)in_sizes; (void)n_in; (void)ws_size; (void)out_size;

  char* ws = (char*)d_ws;
  size_t off = 0;
  auto take = [&](size_t bytes) { void* p = ws + off; off += (bytes + 255) & ~(size_t)255; return p; };

  const long EL2M = 2097152;  // 2048*1024
  const long EL1M = 1048576;  // 1024*1024

  bf16* XB      = (bf16*)take((size_t)EL2M * 2);
  bf16* WQKVOT  = (bf16*)take((size_t)16 * EL1M * 2);  // + SUBW1T/SUBW2T/CONVPWT adjacent
  bf16* SUBW1T  = (bf16*)take((size_t)8 * EL1M * 2);
  bf16* SUBW2T  = (bf16*)take((size_t)8 * EL1M * 2);
  bf16* CONVPWT = (bf16*)take((size_t)EL1M * 2);
  bf16* FUSWT   = (bf16*)take((size_t)EL2M * 2);
  bf16* R1W1T   = (bf16*)take((size_t)512 * 1024 * 2);
  bf16* R2W1T   = (bf16*)take((size_t)4 * 256 * 1024 * 2);
  bf16* PHIWT   = (bf16*)take((size_t)16384 * 2);      // PSIWT adjacent (stride 16384)
  bf16* PSIWT   = (bf16*)take((size_t)16384 * 2);
  float* PHIPSIB = (float*)take((size_t)512 * 4);
  bf16* QKVB    = (bf16*)take((size_t)12 * EL2M * 2);  // + MERGED4 adjacent -> sub arena
  bf16* MERGED4 = (bf16*)take((size_t)4 * EL2M * 2);
  bf16* VTP1    = (bf16*)take((size_t)32 * 128 * 1024 * 2);
  bf16* VT23    = (bf16*)take((size_t)64 * 64 * 1024 * 2);
  bf16* EO      = (bf16*)take((size_t)4 * EL2M * 2);
  bf16* T1      = (bf16*)take((size_t)EL2M * 2);       // dedicated: written early (xprep),
                                                       // must survive SC (full-ARENA) phase
  bf16* ARENA   = (bf16*)take((size_t)64 * 1024 * 1024);
  float* PROBS1 = (float*)take((size_t)2048 * 4 * 4);
  float* PROBS2 = (float*)take((size_t)4 * 2048 * 2 * 4);
  float* TOKIMP = (float*)take((size_t)2048 * 4);
  int*   TOPIDX = (int*)take((size_t)2 * 16 * 4);
  float* VSUMP  = (float*)take((size_t)32 * 16 * 64 * 4);

  // ARENA phase 1 (performer):
  bf16* QPHI  = ARENA;                       // [32][1024][256]
  bf16* KPSI  = ARENA + 8388608;             // [32][1024][256]
  bf16* KPSIT = ARENA + 16777216;            // [32][256][1024]
  bf16* KVTX  = ARENA + 25165824;            // [32][128][256] (row64 = ksum)
  float* DEN  = (float*)(ARENA + 26214400);  // [32][1024]
  // ARENA phase 2 (attention): SC = full 64 MB (clobbers everything in ARENA)
  bf16* SC = ARENA;                          // [32][1024][1024]
  // ARENA phase 3 (late, after SC dead):
  bf16* SUB2F = ARENA;                       // [8][2048][1024] bf16 partials
  float* F32TMP = (float*)(ARENA + 16777216);  // 8 MB
  bf16* H1 = ARENA + 20971520;               // [2048][512]
  bf16* H2 = ARENA + 22020096;               // [4*2048][256]
  bf16* AO = ARENA + 24117248;               // [2048][1024]
  bf16* XC = ARENA + 26214400;               // [2048][1024]
  // sub arena (aliases QKVB+MERGED4, dead by then):
  bf16* SUB1A = QKVB;                        // [8][2048][1024]
  bf16* SUB1B = QKVB + 16777216;             // [8][2048][1024]

  // ---- phase 0: weights + x prep (2 dispatches) ----
  prep_k<<<dim3(32, 64, 42), 256, 0, stream>>>(w_qkvo, sub_w1, sub_w2, conv_pw, fus_w,
                                               r1_w1, r2_w1, phi_w, psi_w, phi_b, psi_b,
                                               WQKVOT, FUSWT, R1W1T, R2W1T,
                                               PHIWT, PSIWT, PHIPSIB, VTP1);
  xprep_k<<<8192, 256, 0, stream>>>(x, conv_dw, XB, T1);

  // ---- QKV for all experts, one batch-12 GEMM ----
  {
    GemmP g = gp0();
    g.A = XB; g.lda = 1024;
    g.B = WQKVOT; g.ldb = 1024; g.sB0 = EL1M; g.sB1 = 4 * EL1M;
    g.C = QKVB; g.ldc = 1024; g.sC0 = EL2M; g.sC1 = 3 * EL2M;
    g.bias = b_qkvo; g.sb0 = 1024; g.sb1 = 4096;
    g.K = 1024; g.inner = 3; g.mode = 0;
    launch_gemm(stream, 0, 2048, 1024, 12, g);
  }

  // ---- expert 0: sparse attention ----
  tokimp_k<<<512, 256, 0, stream>>>(x, sp_w, sp_b, TOKIMP);
  topk_k<<<2, 256, 0, stream>>>(TOKIMP, TOPIDX);
  vsum_k<<<512, 256, 0, stream>>>(QKVB + 2 * EL2M, VSUMP);
  sparse_attn_k<<<dim3(256, 32), 256, 0, stream>>>(QKVB, QKVB + EL2M, QKVB + 2 * EL2M,
                                                   VSUMP, TOPIDX, MERGED4);

  // ---- expert 1: performer ----
  {  // phi(Q) and psi(K) in one batch-64 GEMM (z1 = b + 2*pp)
    GemmP g = gp0();
    g.A = QKVB + 3 * EL2M; g.lda = 1024; g.sA0 = 64; g.sA1 = EL1M;
    g.B = PHIWT; g.ldb = 64; g.sB1 = 16384; g.zBshift = 1;
    g.C = QPHI; g.ldc = 256; g.sC0 = 262144; g.sC1 = 16 * 262144L;
    g.bias = PHIPSIB; g.sb1 = 256;
    g.K = 64; g.inner = 16; g.mode = 4;
    launch_gemm(stream, 0, 1024, 256, 64, g);
  }
  transpose_bf16_k<<<dim3(8, 32, 32), 256, 0, stream>>>(KPSI, KPSIT, 1024, 256, 256,
                                                        32, 1, 262144, 0, 0, 262144);
  transpose_bf16_k<<<dim3(2, 32, 32), 256, 0, stream>>>(QKVB + 5 * EL2M, VTP1, 1024, 64, 1024,
                                                        16, 2, 64, EL1M, 0, 131072);
  {  // KVTX[m,d] = sum_l VTP1[m,l]*KPSIT[d,l]; row 64 = ksum
    GemmP g = gp0();
    g.A = VTP1; g.lda = 1024; g.sA0 = 131072; g.sA1 = 16 * 131072L;
    g.B = KPSIT; g.ldb = 1024; g.sB0 = 262144; g.sB1 = 16 * 262144L;
    g.C = KVTX; g.ldc = 256; g.sC0 = 32768; g.sC1 = 16 * 32768L;
    g.K = 1024; g.inner = 16; g.mode = 0;
    launch_gemm(stream, 1, 128, 256, 32, g);
  }
  den_k<<<8192, 256, 0, stream>>>(QPHI, KVTX, DEN);
  {  // num = qphi @ kv / den -> merged slice 1
    GemmP g = gp0();
    g.A = QPHI; g.lda = 256; g.sA0 = 262144; g.sA1 = 16 * 262144L;
    g.B = KVTX; g.ldb = 256; g.sB0 = 32768; g.sB1 = 16 * 32768L;
    g.C = MERGED4 + EL2M; g.ldc = 1024; g.sC0 = 64; g.sC1 = EL1M;
    g.rowvec = DEN; g.sRV0 = 1024;
    g.K = 256; g.inner = 16; g.mode = 5;
    launch_gemm(stream, 1, 1024, 64, 32, g);
  }

  // ---- V^T for experts 2,3 (batch 64) ----
  transpose_bf16_k<<<dim3(2, 32, 64), 256, 0, stream>>>(QKVB + 8 * EL2M, VT23, 1024, 64, 1024,
                                                        16, 2, 64, EL1M, 3 * EL2M, 65536);

  // ---- experts 2 & 3: softmax attention ----
  for (int e = 2; e <= 3; ++e) {
    const bf16* q = QKVB + (size_t)(e * 3 + 0) * EL2M;
    const bf16* k = QKVB + (size_t)(e * 3 + 1) * EL2M;
    {
      GemmP g = gp0();
      g.A = q; g.lda = 1024; g.sA0 = 64; g.sA1 = EL1M;
      g.B = k; g.ldb = 1024; g.sB0 = 64; g.sB1 = EL1M;
      g.C = SC; g.ldc = 1024; g.sC0 = EL1M; g.sC1 = 16 * EL1M;
      g.K = 64; g.inner = 16; g.scale = 0.125f; g.mode = 0;
      launch_gemm(stream, 0, 1024, 1024, 32, g);
    }
    softmax_rows_k<<<32768, 256, 0, stream>>>(SC);
    {  // P @ V -> merged slice e
      GemmP g = gp0();
      g.A = SC; g.lda = 1024; g.sA0 = EL1M; g.sA1 = 16 * EL1M;
      g.B = VT23 + (size_t)(e - 2) * 32 * 65536; g.ldb = 1024; g.sB0 = 65536; g.sB1 = 16 * 65536L;
      g.C = MERGED4 + (size_t)e * EL2M; g.ldc = 1024; g.sC0 = 64; g.sC1 = EL1M;
      g.K = 1024; g.inner = 16; g.mode = 0;
      launch_gemm(stream, 1, 1024, 64, 32, g);
    }
  }

  // ---- batch-4 output projection (z=3 -> AO) ----
  {
    GemmP g = gp0();
    g.A = MERGED4; g.lda = 1024; g.sA1 = EL2M;
    g.B = WQKVOT + 3 * EL1M; g.ldb = 1024; g.sB1 = 4 * EL1M;
    g.C = EO; g.ldc = 1024; g.sC1 = EL2M;
    g.C2 = AO; g.c2z = 3;
    g.bias = b_qkvo + 3 * 1024; g.sb1 = 4096;
    g.K = 1024; g.mode = 0;
    launch_gemm(stream, 0, 2048, 1024, 4, g);
  }

  // ---- conv branch + fusion ----
  {
    GemmP g = gp0();
    g.A = T1; g.lda = 1024;
    g.B = CONVPWT; g.ldb = 1024;
    g.C = XC; g.ldc = 1024;
    g.K = 1024; g.mode = 3;
    launch_gemm(stream, 1, 2048, 1024, 1, g);
  }
  {  // fusion: A = [AO | XC], K=2048 (SPLIT variant)
    GemmP g = gp0();
    g.A = AO; g.A2 = XC; g.kSplit = 1024; g.lda = 1024;
    g.B = FUSWT; g.ldb = 2048;
    g.C = EO + 3 * EL2M; g.ldc = 1024;
    g.bias = fus_b; g.K = 2048; g.mode = 0;
    launch_gemm(stream, 2, 2048, 1024, 1, g);
  }

  // ---- routers ----
  {
    GemmP g = gp0();
    g.A = XB; g.lda = 1024;
    g.B = R1W1T; g.ldb = 1024;
    g.C = F32TMP; g.ldc = 512;
    g.bias = r1_b1; g.K = 1024; g.mode = 1;
    launch_gemm(stream, 1, 2048, 512, 1, g);
  }
  ln_act_k<<<2048, 256, 0, stream>>>(F32TMP, r1_g, r1_be, H1, 512, 0, 2048, 0);
  router1_k<<<512, 256, 0, stream>>>(H1, r1_w2, r1_b2, PROBS1);
  {
    GemmP g = gp0();
    g.A = EO; g.lda = 1024; g.sA1 = EL2M;
    g.B = R2W1T; g.ldb = 1024; g.sB1 = 262144;
    g.C = F32TMP; g.ldc = 256; g.sC1 = 2048 * 256;
    g.bias = r2_b1; g.sb1 = 256; g.K = 1024; g.mode = 1;
    launch_gemm(stream, 1, 2048, 256, 4, g);
  }
  ln_act_k<<<8192, 256, 0, stream>>>(F32TMP, r2_g, r2_be, H2, 256, 0, 2048, 0);
  router2_k<<<2048, 256, 0, stream>>>(H2, r2_w2, r2_b2, PROBS2, 2048);

  // ---- sub-experts: batch-8 everything ----
  {  // sub1: z = j + 2*i
    GemmP g = gp0();
    g.A = EO; g.lda = 1024; g.sA1 = EL2M;
    g.B = SUBW1T; g.ldb = 1024; g.sB0 = EL1M; g.sB1 = 2 * EL1M;
    g.C = SUB1A; g.ldc = 1024; g.sC0 = EL2M; g.sC1 = 2 * EL2M;
    g.bias = sub_b1; g.sb0 = 1024; g.sb1 = 2048;
    g.K = 1024; g.inner = 2; g.mode = 0;
    launch_gemm(stream, 0, 2048, 1024, 8, g);
  }
  ln_act_k<<<16384, 256, 0, stream>>>(SUB1A, sub_g, sub_be, SUB1B, 1024, 1, 2048, 1);
  {  // sub2 partials (bias folded)
    GemmP g = gp0();
    g.A = SUB1B; g.lda = 1024; g.sA1 = EL2M;
    g.B = SUBW2T; g.ldb = 1024; g.sB1 = EL1M;
    g.C = SUB2F; g.ldc = 1024; g.sC1 = EL2M;
    g.bias = sub_b2; g.sb1 = 1024;
    g.K = 1024; g.mode = 0;
    launch_gemm(stream, 0, 2048, 1024, 8, g);
  }
  combine_k<<<8192, 256, 0, stream>>>(SUB2F, PROBS1, PROBS2, (float*)d_out);
}

// Round 5
// 1038.780 us; speedup vs baseline: 1.7372x; 1.0636x over previous
//
#include <hip/hip_runtime.h>
#include <hip/hip_bf16.h>
#include <cstdint>

using bf16 = __hip_bfloat16;
typedef __attribute__((ext_vector_type(8))) short bfrag;   // 8 x bf16 (4 VGPRs)
typedef __attribute__((ext_vector_type(4))) float ffrag;   // 4 x f32 acc

#define DEV __device__ __forceinline__

DEV float wred_sum(float v) {
#pragma unroll
  for (int o = 32; o > 0; o >>= 1) v += __shfl_xor(v, o, 64);
  return v;
}
DEV float bred_sum(float v) {
  __shared__ float r[4];
  int w = threadIdx.x >> 6, l = threadIdx.x & 63;
  v = wred_sum(v);
  __syncthreads();
  if (l == 0) r[w] = v;
  __syncthreads();
  return r[0] + r[1] + r[2] + r[3];
}
DEV float bred_max(float v) {
  __shared__ float rm[4];
  int w = threadIdx.x >> 6, l = threadIdx.x & 63;
#pragma unroll
  for (int o = 32; o > 0; o >>= 1) v = fmaxf(v, __shfl_xor(v, o, 64));
  __syncthreads();
  if (l == 0) rm[w] = v;
  __syncthreads();
  return fmaxf(fmaxf(rm[0], rm[1]), fmaxf(rm[2], rm[3]));
}
DEV float gelu_f(float x) {  // jax.nn.gelu approximate=True
  float x3 = x * x * x;
  return 0.5f * x * (1.0f + tanhf(0.7978845608028654f * (x + 0.044715f * x3)));
}

// ---------------------------------------------------------------- GEMM (NT)
// C[m,n] = sum_k A[m,k] * B[n,k]
struct GemmP {
  const bf16* A; const bf16* A2; const bf16* B; void* C; void* C2;
  const float* bias; const float* rowvec;
  int K, lda, ldb, ldc, inner, mode, zBshift, c2z, kSplit;
  long sA0, sA1, sB0, sB1, sC0, sC1, sb0, sb1, sRV0;
  float scale;
};
// modes: 0 bf16 store | 1 f32 store | 3 bf16 gelu | 4 bf16 elu+1 | 5 bf16 v/rowvec[z,m]
static GemmP gp0() {
  GemmP g;
  g.A = nullptr; g.A2 = nullptr; g.B = nullptr; g.C = nullptr; g.C2 = nullptr;
  g.bias = nullptr; g.rowvec = nullptr;
  g.K = 0; g.lda = 0; g.ldb = 0; g.ldc = 0; g.inner = 1; g.mode = 0;
  g.zBshift = 0; g.c2z = -1; g.kSplit = 1 << 30;
  g.sA0 = 0; g.sA1 = 0; g.sB0 = 0; g.sB1 = 0; g.sC0 = 0; g.sC1 = 0;
  g.sb0 = 0; g.sb1 = 0; g.sRV0 = 0; g.scale = 1.f;
  return g;
}

// LDS bank-conflict swizzle: row r of a tile stores its four 16-B chunks
// permuted by c_lds = c_glob ^ ((r>>1)&3). Staging picks the global chunk
// per lane accordingly (global_load_lds dest stays base + lane*16); the
// fragment read applies the same XOR. Makes the 16 fr-lanes of a
// ds_read_b128 hit all 8 chunk-slots (2-way = free) instead of 2 (8-way).
template <int BM, int BN, int WM, int WN, bool SPLIT>
__global__ __launch_bounds__(256)
void gemm_nt(GemmP p) {
  constexpr int TI = BM / (WM * 16), TJ = BN / (WN * 16);
  __shared__ bf16 smem[(BM + BN) * 32];
  const int tid = threadIdx.x;
  const int z = blockIdx.z;
  const int z0 = z % p.inner, z1 = z / p.inner;
  const long zB = (long)(z1 >> p.zBshift);
  const bf16* A = p.A + (long)z0 * p.sA0 + (long)z1 * p.sA1;
  const bf16* Bp = p.B + (long)z0 * p.sB0 + zB * p.sB1;
  const int m0 = blockIdx.x * BM, n0 = blockIdx.y * BN;
  const int wave = tid >> 6, lane = tid & 63;
  const int wrow = wave / WN, wcol = wave % WN;
  const int fr = lane & 15, quad = lane >> 4;
  const int swz = (quad ^ ((fr >> 1) & 3)) * 8;   // element offset of swizzled chunk
  ffrag acc[TI][TJ] = {};
  constexpr int CH_A = BM * 4;
  constexpr int NIT = (BM + BN) * 4 / 256;
  for (int k0 = 0; k0 < p.K; k0 += 32) {
    const bf16* Asrc = A;
    int kc = k0;
    if constexpr (SPLIT) {
      if (k0 >= p.kSplit) { Asrc = p.A2; kc = k0 - p.kSplit; }
    }
#pragma unroll
    for (int it = 0; it < NIT; ++it) {
      int idx = it * 256 + tid;
      const bf16* g;
      if (idx < CH_A) {
        int r = idx >> 2, c = (idx & 3) ^ ((idx >> 3) & 3);
        g = Asrc + (long)(m0 + r) * p.lda + kc + c * 8;
      } else {
        int j = idx - CH_A;
        int r = j >> 2, c = (j & 3) ^ ((j >> 3) & 3);
        g = Bp + (long)(n0 + r) * p.ldb + k0 + c * 8;
      }
      __builtin_amdgcn_global_load_lds(
          (const __attribute__((address_space(1))) void*)g,
          (__attribute__((address_space(3))) void*)(smem + idx * 8), 16, 0, 0);
    }
    __syncthreads();
    bfrag af[TI], bfb[TJ];
#pragma unroll
    for (int t = 0; t < TI; ++t)
      af[t] = *(const bfrag*)(smem + ((wrow * (TI * 16) + t * 16 + fr) * 32 + swz));
#pragma unroll
    for (int t = 0; t < TJ; ++t)
      bfb[t] = *(const bfrag*)(smem + (BM * 32 + (wcol * (TJ * 16) + t * 16 + fr) * 32 + swz));
#pragma unroll
    for (int ti = 0; ti < TI; ++ti)
#pragma unroll
      for (int tj = 0; tj < TJ; ++tj)
        acc[ti][tj] = __builtin_amdgcn_mfma_f32_16x16x32_bf16(af[ti], bfb[tj], acc[ti][tj], 0, 0, 0);
    __syncthreads();
  }
  const int mbase = m0 + wrow * (TI * 16), nbase = n0 + wcol * (TJ * 16);
  void* Cb = p.C;
  long zc = (long)z0 * p.sC0 + (long)z1 * p.sC1;
  if (z == p.c2z) { Cb = p.C2; zc = 0; }
  const long zb = (long)z0 * p.sb0 + zB * p.sb1;
#pragma unroll
  for (int ti = 0; ti < TI; ++ti) {
#pragma unroll
    for (int tj = 0; tj < TJ; ++tj) {
#pragma unroll
      for (int r = 0; r < 4; ++r) {
        int m = mbase + ti * 16 + quad * 4 + r;
        int n = nbase + tj * 16 + fr;
        float v = acc[ti][tj][r] * p.scale;
        if (p.bias) v += p.bias[zb + n];
        long ci = zc + (long)m * p.ldc + n;
        if (p.mode == 0) ((bf16*)Cb)[ci] = __float2bfloat16(v);
        else if (p.mode == 1) ((float*)Cb)[ci] = v;
        else if (p.mode == 3) ((bf16*)Cb)[ci] = __float2bfloat16(gelu_f(v));
        else if (p.mode == 4) ((bf16*)Cb)[ci] = __float2bfloat16(v > 0.f ? v + 1.f : __expf(v));
        else {
          float d = p.rowvec[(long)z * p.sRV0 + m];
          ((bf16*)Cb)[ci] = __float2bfloat16(v / d);
        }
      }
    }
  }
}

// cfg 0: 128x128 | 1: 128x64 | 2: 64x64 (starved/small GEMMs) | 3: 64x64 split-A
static void launch_gemm(hipStream_t st, int cfg, int M, int N, int batch, const GemmP& g) {
  dim3 bs(256);
  if (cfg == 0)      gemm_nt<128, 128, 2, 2, false><<<dim3(M / 128, N / 128, batch), bs, 0, st>>>(g);
  else if (cfg == 1) gemm_nt<128, 64, 2, 2, false><<<dim3(M / 128, N / 64, batch), bs, 0, st>>>(g);
  else if (cfg == 2) gemm_nt<64, 64, 2, 2, false><<<dim3(M / 64, N / 64, batch), bs, 0, st>>>(g);
  else               gemm_nt<64, 64, 2, 2, true><<<dim3(M / 64, N / 64, batch), bs, 0, st>>>(g);
}

// ---------------------------------------------------------------- prep (all weight transposes)
// grid (32, 64, 42); src[R][C] f32 -> dst[C][R] bf16, demuxed on z
__global__ void prep_k(const float* w_qkvo, const float* sub_w1, const float* sub_w2,
                       const float* conv_pw, const float* fus_w, const float* r1_w1,
                       const float* r2_w1, const float* phi_w, const float* psi_w,
                       const float* phi_b, const float* psi_b,
                       bf16* wt, bf16* fuswt, bf16* r1w1t, bf16* r2w1t,
                       bf16* phiwt, bf16* psiwt, float* phipsib, bf16* vtp1) {
  int z = blockIdx.z;
  int bx = blockIdx.x, by = blockIdx.y;
  int tx = threadIdx.x & 31, ty = threadIdx.x >> 5;
  const float* src; bf16* dst; int R, C;
  if (z < 33) {
    if (by >= 32) return;
    src = z < 16 ? w_qkvo + (long)z * 1048576
        : z < 24 ? sub_w1 + (long)(z - 16) * 1048576
        : z < 32 ? sub_w2 + (long)(z - 24) * 1048576
                 : conv_pw;
    dst = wt + (long)z * 1048576; R = 1024; C = 1024;
  } else if (z == 33) {
    src = fus_w; dst = fuswt; R = 2048; C = 1024;
  } else if (z == 34) {
    if (bx >= 16 || by >= 32) return;
    src = r1_w1; dst = r1w1t; R = 1024; C = 512;
  } else if (z < 39) {
    if (bx >= 8 || by >= 32) return;
    src = r2_w1 + (long)(z - 35) * 262144; dst = r2w1t + (long)(z - 35) * 262144;
    R = 1024; C = 256;
  } else if (z < 41) {
    if (bx >= 8 || by >= 2) return;
    src = (z == 39) ? phi_w : psi_w; dst = (z == 39) ? phiwt : psiwt; R = 64; C = 256;
  } else {
    if (by == 0) {  // ones row (performer ksum trick): slice bx of VTP1
      for (int c = threadIdx.x; c < 1024; c += 256)
        vtp1[(long)bx * 131072 + 65536 + c] = __float2bfloat16(1.0f);
    } else if (by == 1 && bx == 0) {
      for (int i = threadIdx.x; i < 512; i += 256)
        phipsib[i] = i < 256 ? phi_b[i] : psi_b[i - 256];
    }
    return;
  }
  __shared__ float t[32][33];
  int c0 = bx * 32, r0 = by * 32;
#pragma unroll
  for (int i = 0; i < 32; i += 8)
    t[ty + i][tx] = src[(long)(r0 + ty + i) * C + c0 + tx];
  __syncthreads();
#pragma unroll
  for (int i = 0; i < 32; i += 8)
    dst[(long)(c0 + ty + i) * R + r0 + tx] = __float2bfloat16(t[tx][ty + i]);
}

// x -> bf16 copy + depthwise conv branch, one pass over x
__global__ void xprep_k(const float* x, const float* dw, bf16* xb, bf16* t1) {
  long i = (long)blockIdx.x * 256 + threadIdx.x;
  float xv = x[i];
  xb[i] = __float2bfloat16(xv);
  int d = (int)(i & 1023);
  long row = i >> 10;
  int s = (int)(row & 1023);
  float a = xv * dw[1024 + d];
  if (s > 0) a += x[i - 1024] * dw[d];
  if (s < 1023) a += x[i + 1024] * dw[2048 + d];
  t1[i] = __float2bfloat16(a);
}

// bf16 strided [z](R x C, row stride rs) -> bf16 out + z*ldz, out[c*R + r]
// z = z0 + inner*(z1 + inner2*z2), input offset z0*is0 + z1*is1 + z2*is2
__global__ void transpose_bf16_k(const bf16* in, bf16* outp, int R, int C, int rs,
                                 int inner, int inner2, long is0, long is1, long is2,
                                 long ldz) {
  __shared__ bf16 t[32][33];
  int z = blockIdx.z;
  int z0 = z % inner; int zr = z / inner;
  int z1 = zr % inner2; int z2 = zr / inner2;
  long zo = (long)z0 * is0 + (long)z1 * is1 + (long)z2 * is2;
  int c0 = blockIdx.x * 32, r0 = blockIdx.y * 32;
  int tx = threadIdx.x & 31, ty = threadIdx.x >> 5;
#pragma unroll
  for (int i = 0; i < 32; i += 8)
    t[ty + i][tx] = in[zo + (long)(r0 + ty + i) * rs + c0 + tx];
  __syncthreads();
  long ob = (long)z * ldz;
#pragma unroll
  for (int i = 0; i < 32; i += 8)
    outp[ob + (long)(c0 + ty + i) * R + r0 + tx] = t[tx][ty + i];
}

__global__ void softmax_rows_k(bf16* sc) {  // N = 1024, in-place
  long row = blockIdx.x;
  bf16* p = sc + row * 1024;
  int tid = threadIdx.x;
  float v[4];
  float lm = -1e30f;
#pragma unroll
  for (int i = 0; i < 4; ++i) { v[i] = __bfloat162float(p[tid + i * 256]); lm = fmaxf(lm, v[i]); }
  float m = bred_max(lm);
  float ls = 0.f;
#pragma unroll
  for (int i = 0; i < 4; ++i) { v[i] = __expf(v[i] - m); ls += v[i]; }
  float inv = 1.0f / bred_sum(ls);
#pragma unroll
  for (int i = 0; i < 4; ++i) p[tid + i * 256] = __float2bfloat16(v[i] * inv);
}

// LN + act, single global read (register cache), N <= 1024
__global__ void ln_act_k(const void* in, const float* gamma, const float* beta,
                         bf16* outp, int N, int act, int rows_per_seg, int in_bf16) {
  long row = blockIdx.x;
  int tid = threadIdx.x;
  const bf16* ib = (const bf16*)in;
  const float* iff = (const float*)in;
  float vc[4];
  float ls = 0.f;
  int i = 0;
  for (int c = tid; c < N; c += 256, ++i) {
    float v = in_bf16 ? __bfloat162float(ib[row * N + c]) : iff[row * N + c];
    vc[i] = v; ls += v;
  }
  float mean = bred_sum(ls) / N;
  float lv = 0.f;
  i = 0;
  for (int c = tid; c < N; c += 256, ++i) { float d = vc[i] - mean; lv += d * d; }
  float rstd = rsqrtf(bred_sum(lv) / N + 1e-5f);
  long go = (row / rows_per_seg) * (long)N;
  const float* gp = gamma + go;
  const float* bp = beta + go;
  i = 0;
  for (int c = tid; c < N; c += 256, ++i) {
    float v = (vc[i] - mean) * rstd * gp[c] + bp[c];
    v = act ? gelu_f(v) : fmaxf(v, 0.f);
    outp[row * N + c] = __float2bfloat16(v);
  }
}

__global__ void tokimp_k(const float* x, const float* spw, const float* spb, float* outp) {
  int row = blockIdx.x * 4 + (threadIdx.x >> 6);
  int l = threadIdx.x & 63;
  const float* xp = x + (long)row * 1024;
  float a = 0.f;
  for (int c = l; c < 1024; c += 64) a += xp[c] * spw[c];
  a = wred_sum(a);
  if (l == 0) outp[row] = a + spb[0];
}

__global__ void topk_k(const float* timp, int* outp) {
  __shared__ float vals[1024];
  __shared__ float wv[4];
  __shared__ int wi[4];
  int b = blockIdx.x, tid = threadIdx.x;
  for (int c = tid; c < 1024; c += 256) vals[c] = timp[b * 1024 + c];
  __syncthreads();
  for (int t = 0; t < 10; ++t) {
    float bv = -3.0e38f; int bi = 1 << 30;
    for (int c = tid; c < 1024; c += 256) {
      float v = vals[c];
      if (v > bv || (v == bv && c < bi)) { bv = v; bi = c; }
    }
#pragma unroll
    for (int o = 32; o > 0; o >>= 1) {
      float ov = __shfl_xor(bv, o, 64); int oi = __shfl_xor(bi, o, 64);
      if (ov > bv || (ov == bv && oi < bi)) { bv = ov; bi = oi; }
    }
    int w = tid >> 6, l = tid & 63;
    if (l == 0) { wv[w] = bv; wi[w] = bi; }
    __syncthreads();
    if (tid == 0) {
      float fv = wv[0]; int fi = wi[0];
      for (int ww = 1; ww < 4; ++ww)
        if (wv[ww] > fv || (wv[ww] == fv && wi[ww] < fi)) { fv = wv[ww]; fi = wi[ww]; }
      outp[b * 16 + t] = fi;
      vals[fi] = -3.0e38f;
    }
    __syncthreads();
  }
}

// stage-1 V column sums: 512 blocks, partials [32][16][64]
__global__ void vsum_k(const bf16* v, float* vsump) {
  __shared__ float red[4][64];
  int zz = blockIdx.x;
  int z = zz >> 4, slab = zz & 15;
  int b = z >> 4, h = z & 15;
  const bf16* vp = v + (long)b * 1048576 + h * 64;
  int d = threadIdx.x & 63, sg = threadIdx.x >> 6;
  float s = 0.f;
#pragma unroll
  for (int i = 0; i < 16; ++i) {
    int srow = slab * 64 + sg * 16 + i;
    s += __bfloat162float(vp[(long)srow * 1024 + d]);
  }
  red[sg][d] = s;
  __syncthreads();
  if (sg == 0) vsump[(long)zz * 64 + d] = red[0][d] + red[1][d] + red[2][d] + red[3][d];
}

// expert-0 sparse attention, algebraically reduced
__global__ void sparse_attn_k(const bf16* q, const bf16* k, const bf16* v,
                              const float* vsump, const int* topidx, bf16* merged) {
  __shared__ float kt[10][64], vt[10][64], vs[64], vts[64];
  int z = blockIdx.y, b = z >> 4, h = z & 15;
  int tid = threadIdx.x;
  const int* tix = topidx + b * 16;
  for (int t = tid; t < 640; t += 256) {
    int tt = t >> 6, d = t & 63;
    long src = ((long)b * 1024 + tix[tt]) * 1024 + h * 64 + d;
    kt[tt][d] = __bfloat162float(k[src]);
    vt[tt][d] = __bfloat162float(v[src]);
  }
  if (tid < 64) {
    float s = 0.f;
#pragma unroll
    for (int p = 0; p < 16; ++p) s += vsump[((long)z * 16 + p) * 64 + tid];
    vs[tid] = s;
  }
  __syncthreads();
  if (tid < 64) {
    float s = 0.f;
#pragma unroll
    for (int t = 0; t < 10; ++t) s += vt[t][tid];
    vts[tid] = s;
  }
  __syncthreads();
  int wave = tid >> 6, lane = tid & 63;
  int sq = blockIdx.x * 4 + wave;
  long qi = ((long)b * 1024 + sq) * 1024 + h * 64 + lane;
  float qd = __bfloat162float(q[qi]);
  float sc[10];
#pragma unroll
  for (int t = 0; t < 10; ++t) sc[t] = wred_sum(qd * kt[t][lane]) * 0.125f;
  float m = 0.f;
#pragma unroll
  for (int t = 0; t < 10; ++t) m = fmaxf(m, sc[t]);
  float e[10], se = 0.f;
#pragma unroll
  for (int t = 0; t < 10; ++t) { e[t] = __expf(sc[t] - m); se += e[t]; }
  float em = __expf(-m);
  float Z = 1014.f * em + se;
  float o = em * (vs[lane] - vts[lane]);
#pragma unroll
  for (int t = 0; t < 10; ++t) o += e[t] * vt[t][lane];
  merged[qi] = __float2bfloat16(o / Z);
}

// den = qphi . ksum (+1e-8); ksum = row 64 of KVTX slices
__global__ void den_k(const bf16* qphi, const bf16* kvtx, float* den) {
  int r = blockIdx.x * 4 + (threadIdx.x >> 6);
  int l = threadIdx.x & 63;
  int z = r >> 10;
  const bf16* qp = qphi + (long)r * 256;
  const bf16* ks = kvtx + (long)z * 32768 + 16384;
  float a = 0.f;
  for (int c = l; c < 256; c += 64) a += __bfloat162float(qp[c]) * __bfloat162float(ks[c]);
  a = wred_sum(a);
  if (l == 0) den[r] = a + 1e-8f;
}

__global__ void router1_k(const bf16* h1, const float* w, const float* bias, float* outp) {
  int row = blockIdx.x * 4 + (threadIdx.x >> 6);
  int l = threadIdx.x & 63;
  const bf16* hp = h1 + (long)row * 512;
  float a0 = 0, a1 = 0, a2 = 0, a3 = 0;
  for (int c = l; c < 512; c += 64) {
    float hv = __bfloat162float(hp[c]);
    const float* wp = w + c * 4;
    a0 += hv * wp[0]; a1 += hv * wp[1]; a2 += hv * wp[2]; a3 += hv * wp[3];
  }
  a0 = wred_sum(a0); a1 = wred_sum(a1); a2 = wred_sum(a2); a3 = wred_sum(a3);
  a0 += bias[0]; a1 += bias[1]; a2 += bias[2]; a3 += bias[3];
  float m = fmaxf(fmaxf(a0, a1), fmaxf(a2, a3));
  float e0 = __expf(a0 - m), e1 = __expf(a1 - m), e2 = __expf(a2 - m), e3 = __expf(a3 - m);
  float inv = 1.f / (e0 + e1 + e2 + e3);
  if (l == 0) {
    float* op = outp + (long)row * 4;
    op[0] = e0 * inv; op[1] = e1 * inv; op[2] = e2 * inv; op[3] = e3 * inv;
  }
}

__global__ void router2_k(const bf16* h2, const float* w, const float* bias, float* outp,
                          int rows_per_seg) {
  int row = blockIdx.x * 4 + (threadIdx.x >> 6);
  int l = threadIdx.x & 63;
  int seg = row / rows_per_seg;
  const float* wp = w + (long)seg * 512;
  const float* bp = bias + (long)seg * 2;
  const bf16* hp = h2 + (long)row * 256;
  float a0 = 0, a1 = 0;
  for (int c = l; c < 256; c += 64) {
    float hv = __bfloat162float(hp[c]);
    a0 += hv * wp[c * 2]; a1 += hv * wp[c * 2 + 1];
  }
  a0 = wred_sum(a0); a1 = wred_sum(a1);
  a0 += bp[0]; a1 += bp[1];
  float m = fmaxf(a0, a1);
  float e0 = __expf(a0 - m), e1 = __expf(a1 - m);
  float inv = 1.f / (e0 + e1);
  if (l == 0) { outp[(long)row * 2] = e0 * inv; outp[(long)row * 2 + 1] = e1 * inv; }
}

// final: out[m,n] = sum_z p1[m][z/2] * p2[z/2][m][z&1] * part[z][m][n]
__global__ void combine_k(const bf16* part, const float* p1, const float* p2, float* outp) {
  long i = (long)blockIdx.x * 256 + threadIdx.x;
  long m = i >> 10;
  float acc = 0.f;
#pragma unroll
  for (int zz = 0; zz < 8; ++zz) {
    int e = zz >> 1, j = zz & 1;
    float w = p1[m * 4 + e] * p2[(long)e * 4096 + m * 2 + j];
    acc += w * __bfloat162float(part[(long)zz * 2097152 + i]);
  }
  outp[i] = acc;
}

// ---------------------------------------------------------------- host
extern "C" void kernel_launch(void* const* d_in, const int* in_sizes, int n_in,
                              void* d_out, int out_size, void* d_ws, size_t ws_size,
                              hipStream_t stream) {
  const float* x = (const float*)d_in[0];
  const float* w_qkvo = (const float*)d_in[1];
  const float* b_qkvo = (const float*)d_in[2];
  const float* sp_w = (const float*)d_in[3];
  const float* sp_b = (const float*)d_in[4];
  const float* phi_w = (const float*)d_in[5];
  const float* phi_b = (const float*)d_in[6];
  const float* psi_w = (const float*)d_in[7];
  const float* psi_b = (const float*)d_in[8];
  const float* conv_dw = (const float*)d_in[9];
  const float* conv_pw = (const float*)d_in[10];
  const float* fus_w = (const float*)d_in[11];
  const float* fus_b = (const float*)d_in[12];
  const float* sub_w1 = (const float*)d_in[13];
  const float* sub_b1 = (const float*)d_in[14];
  const float* sub_g = (const float*)d_in[15];
  const float* sub_be = (const float*)d_in[16];
  const float* sub_w2 = (const float*)d_in[17];
  const float* sub_b2 = (const float*)d_in[18];
  const float* r1_w1 = (const float*)d_in[19];
  const float* r1_b1 = (const float*)d_in[20];
  const float* r1_g = (const float*)d_in[21];
  const float* r1_be = (const float*)d_in[22];
  const float* r1_w2 = (const float*)d_in[23];
  const float* r1_b2 = (const float*)d_in[24];
  const float* r2_w1 = (const float*)d_in[25];
  const float* r2_b1 = (const float*)d_in[26];
  const float* r2_g = (const float*)d_in[27];
  const float* r2_be = (const float*)d_in[28];
  const float* r2_w2 = (const float*)d_in[29];
  const float* r2_b2 = (const float*)d_in[30];
  (void)in_sizes; (void)n_in; (void)ws_size; (void)out_size;

  char* ws = (char*)d_ws;
  size_t off = 0;
  auto take = [&](size_t bytes) { void* p = ws + off; off += (bytes + 255) & ~(size_t)255; return p; };

  const long EL2M = 2097152;  // 2048*1024
  const long EL1M = 1048576;  // 1024*1024

  bf16* XB      = (bf16*)take((size_t)EL2M * 2);
  bf16* WQKVOT  = (bf16*)take((size_t)16 * EL1M * 2);  // + SUBW1T/SUBW2T/CONVPWT adjacent
  bf16* SUBW1T  = (bf16*)take((size_t)8 * EL1M * 2);
  bf16* SUBW2T  = (bf16*)take((size_t)8 * EL1M * 2);
  bf16* CONVPWT = (bf16*)take((size_t)EL1M * 2);
  bf16* FUSWT   = (bf16*)take((size_t)EL2M * 2);
  bf16* R1W1T   = (bf16*)take((size_t)512 * 1024 * 2);
  bf16* R2W1T   = (bf16*)take((size_t)4 * 256 * 1024 * 2);
  bf16* PHIWT   = (bf16*)take((size_t)16384 * 2);      // PSIWT adjacent (stride 16384)
  bf16* PSIWT   = (bf16*)take((size_t)16384 * 2);
  float* PHIPSIB = (float*)take((size_t)512 * 4);
  bf16* QKVB    = (bf16*)take((size_t)12 * EL2M * 2);  // + MERGED4 adjacent -> sub arena
  bf16* MERGED4 = (bf16*)take((size_t)4 * EL2M * 2);
  bf16* VTP1    = (bf16*)take((size_t)32 * 128 * 1024 * 2);
  bf16* VT23    = (bf16*)take((size_t)64 * 64 * 1024 * 2);
  bf16* EO      = (bf16*)take((size_t)4 * EL2M * 2);
  bf16* T1      = (bf16*)take((size_t)EL2M * 2);       // dedicated: written early (xprep),
                                                       // must survive SC (full-ARENA) phase
  bf16* ARENA   = (bf16*)take((size_t)64 * 1024 * 1024);
  float* PROBS1 = (float*)take((size_t)2048 * 4 * 4);
  float* PROBS2 = (float*)take((size_t)4 * 2048 * 2 * 4);
  float* TOKIMP = (float*)take((size_t)2048 * 4);
  int*   TOPIDX = (int*)take((size_t)2 * 16 * 4);
  float* VSUMP  = (float*)take((size_t)32 * 16 * 64 * 4);

  // ARENA phase 1 (performer):
  bf16* QPHI  = ARENA;                       // [32][1024][256]
  bf16* KPSI  = ARENA + 8388608;             // [32][1024][256]
  bf16* KPSIT = ARENA + 16777216;            // [32][256][1024]
  bf16* KVTX  = ARENA + 25165824;            // [32][128][256] (row64 = ksum)
  float* DEN  = (float*)(ARENA + 26214400);  // [32][1024]
  // ARENA phase 2 (attention): SC = full 64 MB (clobbers everything in ARENA)
  bf16* SC = ARENA;                          // [32][1024][1024]
  // ARENA phase 3 (late, after SC dead):
  bf16* SUB2F = ARENA;                       // [8][2048][1024] bf16 partials
  float* F32TMP = (float*)(ARENA + 16777216);  // 8 MB
  bf16* H1 = ARENA + 20971520;               // [2048][512]
  bf16* H2 = ARENA + 22020096;               // [4*2048][256]
  bf16* AO = ARENA + 24117248;               // [2048][1024]
  bf16* XC = ARENA + 26214400;               // [2048][1024]
  // sub arena (aliases QKVB+MERGED4, dead by then):
  bf16* SUB1A = QKVB;                        // [8][2048][1024]
  bf16* SUB1B = QKVB + 16777216;             // [8][2048][1024]

  // ---- phase 0: weights + x prep (2 dispatches) ----
  prep_k<<<dim3(32, 64, 42), 256, 0, stream>>>(w_qkvo, sub_w1, sub_w2, conv_pw, fus_w,
                                               r1_w1, r2_w1, phi_w, psi_w, phi_b, psi_b,
                                               WQKVOT, FUSWT, R1W1T, R2W1T,
                                               PHIWT, PSIWT, PHIPSIB, VTP1);
  xprep_k<<<8192, 256, 0, stream>>>(x, conv_dw, XB, T1);

  // ---- QKV for all experts, one batch-12 GEMM ----
  {
    GemmP g = gp0();
    g.A = XB; g.lda = 1024;
    g.B = WQKVOT; g.ldb = 1024; g.sB0 = EL1M; g.sB1 = 4 * EL1M;
    g.C = QKVB; g.ldc = 1024; g.sC0 = EL2M; g.sC1 = 3 * EL2M;
    g.bias = b_qkvo; g.sb0 = 1024; g.sb1 = 4096;
    g.K = 1024; g.inner = 3; g.mode = 0;
    launch_gemm(stream, 0, 2048, 1024, 12, g);
  }

  // ---- expert 0: sparse attention ----
  tokimp_k<<<512, 256, 0, stream>>>(x, sp_w, sp_b, TOKIMP);
  topk_k<<<2, 256, 0, stream>>>(TOKIMP, TOPIDX);
  vsum_k<<<512, 256, 0, stream>>>(QKVB + 2 * EL2M, VSUMP);
  sparse_attn_k<<<dim3(256, 32), 256, 0, stream>>>(QKVB, QKVB + EL2M, QKVB + 2 * EL2M,
                                                   VSUMP, TOPIDX, MERGED4);

  // ---- expert 1: performer ----
  {  // phi(Q) and psi(K) in one batch-64 GEMM (z1 = b + 2*pp)
    GemmP g = gp0();
    g.A = QKVB + 3 * EL2M; g.lda = 1024; g.sA0 = 64; g.sA1 = EL1M;
    g.B = PHIWT; g.ldb = 64; g.sB1 = 16384; g.zBshift = 1;
    g.C = QPHI; g.ldc = 256; g.sC0 = 262144; g.sC1 = 16 * 262144L;
    g.bias = PHIPSIB; g.sb1 = 256;
    g.K = 64; g.inner = 16; g.mode = 4;
    launch_gemm(stream, 2, 1024, 256, 64, g);
  }
  transpose_bf16_k<<<dim3(8, 32, 32), 256, 0, stream>>>(KPSI, KPSIT, 1024, 256, 256,
                                                        32, 1, 262144, 0, 0, 262144);
  transpose_bf16_k<<<dim3(2, 32, 32), 256, 0, stream>>>(QKVB + 5 * EL2M, VTP1, 1024, 64, 1024,
                                                        16, 2, 64, EL1M, 0, 131072);
  {  // KVTX[m,d] = sum_l VTP1[m,l]*KPSIT[d,l]; row 64 = ksum
    GemmP g = gp0();
    g.A = VTP1; g.lda = 1024; g.sA0 = 131072; g.sA1 = 16 * 131072L;
    g.B = KPSIT; g.ldb = 1024; g.sB0 = 262144; g.sB1 = 16 * 262144L;
    g.C = KVTX; g.ldc = 256; g.sC0 = 32768; g.sC1 = 16 * 32768L;
    g.K = 1024; g.inner = 16; g.mode = 0;
    launch_gemm(stream, 2, 128, 256, 32, g);
  }
  den_k<<<8192, 256, 0, stream>>>(QPHI, KVTX, DEN);
  {  // num = qphi @ kv / den -> merged slice 1
    GemmP g = gp0();
    g.A = QPHI; g.lda = 256; g.sA0 = 262144; g.sA1 = 16 * 262144L;
    g.B = KVTX; g.ldb = 256; g.sB0 = 32768; g.sB1 = 16 * 32768L;
    g.C = MERGED4 + EL2M; g.ldc = 1024; g.sC0 = 64; g.sC1 = EL1M;
    g.rowvec = DEN; g.sRV0 = 1024;
    g.K = 256; g.inner = 16; g.mode = 5;
    launch_gemm(stream, 2, 1024, 64, 32, g);
  }

  // ---- V^T for experts 2,3 (batch 64) ----
  transpose_bf16_k<<<dim3(2, 32, 64), 256, 0, stream>>>(QKVB + 8 * EL2M, VT23, 1024, 64, 1024,
                                                        16, 2, 64, EL1M, 3 * EL2M, 65536);

  // ---- experts 2 & 3: softmax attention ----
  for (int e = 2; e <= 3; ++e) {
    const bf16* q = QKVB + (size_t)(e * 3 + 0) * EL2M;
    const bf16* k = QKVB + (size_t)(e * 3 + 1) * EL2M;
    {
      GemmP g = gp0();
      g.A = q; g.lda = 1024; g.sA0 = 64; g.sA1 = EL1M;
      g.B = k; g.ldb = 1024; g.sB0 = 64; g.sB1 = EL1M;
      g.C = SC; g.ldc = 1024; g.sC0 = EL1M; g.sC1 = 16 * EL1M;
      g.K = 64; g.inner = 16; g.scale = 0.125f; g.mode = 0;
      launch_gemm(stream, 0, 1024, 1024, 32, g);
    }
    softmax_rows_k<<<32768, 256, 0, stream>>>(SC);
    {  // P @ V -> merged slice e
      GemmP g = gp0();
      g.A = SC; g.lda = 1024; g.sA0 = EL1M; g.sA1 = 16 * EL1M;
      g.B = VT23 + (size_t)(e - 2) * 32 * 65536; g.ldb = 1024; g.sB0 = 65536; g.sB1 = 16 * 65536L;
      g.C = MERGED4 + (size_t)e * EL2M; g.ldc = 1024; g.sC0 = 64; g.sC1 = EL1M;
      g.K = 1024; g.inner = 16; g.mode = 0;
      launch_gemm(stream, 2, 1024, 64, 32, g);
    }
  }

  // ---- batch-4 output projection (z=3 -> AO) ----
  {
    GemmP g = gp0();
    g.A = MERGED4; g.lda = 1024; g.sA1 = EL2M;
    g.B = WQKVOT + 3 * EL1M; g.ldb = 1024; g.sB1 = 4 * EL1M;
    g.C = EO; g.ldc = 1024; g.sC1 = EL2M;
    g.C2 = AO; g.c2z = 3;
    g.bias = b_qkvo + 3 * 1024; g.sb1 = 4096;
    g.K = 1024; g.mode = 0;
    launch_gemm(stream, 0, 2048, 1024, 4, g);
  }

  // ---- conv branch + fusion ----
  {
    GemmP g = gp0();
    g.A = T1; g.lda = 1024;
    g.B = CONVPWT; g.ldb = 1024;
    g.C = XC; g.ldc = 1024;
    g.K = 1024; g.mode = 3;
    launch_gemm(stream, 2, 2048, 1024, 1, g);
  }
  {  // fusion: A = [AO | XC], K=2048 (SPLIT variant)
    GemmP g = gp0();
    g.A = AO; g.A2 = XC; g.kSplit = 1024; g.lda = 1024;
    g.B = FUSWT; g.ldb = 2048;
    g.C = EO + 3 * EL2M; g.ldc = 1024;
    g.bias = fus_b; g.K = 2048; g.mode = 0;
    launch_gemm(stream, 3, 2048, 1024, 1, g);
  }

  // ---- routers ----
  {
    GemmP g = gp0();
    g.A = XB; g.lda = 1024;
    g.B = R1W1T; g.ldb = 1024;
    g.C = F32TMP; g.ldc = 512;
    g.bias = r1_b1; g.K = 1024; g.mode = 1;
    launch_gemm(stream, 2, 2048, 512, 1, g);
  }
  ln_act_k<<<2048, 256, 0, stream>>>(F32TMP, r1_g, r1_be, H1, 512, 0, 2048, 0);
  router1_k<<<512, 256, 0, stream>>>(H1, r1_w2, r1_b2, PROBS1);
  {
    GemmP g = gp0();
    g.A = EO; g.lda = 1024; g.sA1 = EL2M;
    g.B = R2W1T; g.ldb = 1024; g.sB1 = 262144;
    g.C = F32TMP; g.ldc = 256; g.sC1 = 2048 * 256;
    g.bias = r2_b1; g.sb1 = 256; g.K = 1024; g.mode = 1;
    launch_gemm(stream, 2, 2048, 256, 4, g);
  }
  ln_act_k<<<8192, 256, 0, stream>>>(F32TMP, r2_g, r2_be, H2, 256, 0, 2048, 0);
  router2_k<<<2048, 256, 0, stream>>>(H2, r2_w2, r2_b2, PROBS2, 2048);

  // ---- sub-experts: batch-8 everything ----
  {  // sub1: z = j + 2*i
    GemmP g = gp0();
    g.A = EO; g.lda = 1024; g.sA1 = EL2M;
    g.B = SUBW1T; g.ldb = 1024; g.sB0 = EL1M; g.sB1 = 2 * EL1M;
    g.C = SUB1A; g.ldc = 1024; g.sC0 = EL2M; g.sC1 = 2 * EL2M;
    g.bias = sub_b1; g.sb0 = 1024; g.sb1 = 2048;
    g.K = 1024; g.inner = 2; g.mode = 0;
    launch_gemm(stream, 0, 2048, 1024, 8, g);
  }
  ln_act_k<<<16384, 256, 0, stream>>>(SUB1A, sub_g, sub_be, SUB1B, 1024, 1, 2048, 1);
  {  // sub2 partials (bias folded)
    GemmP g = gp0();
    g.A = SUB1B; g.lda = 1024; g.sA1 = EL2M;
    g.B = SUBW2T; g.ldb = 1024; g.sB1 = EL1M;
    g.C = SUB2F; g.ldc = 1024; g.sC1 = EL2M;
    g.bias = sub_b2; g.sb1 = 1024;
    g.K = 1024; g.mode = 0;
    launch_gemm(stream, 0, 2048, 1024, 8, g);
  }
  combine_k<<<8192, 256, 0, stream>>>(SUB2F, PROBS1, PROBS2, (float*)d_out);
}

// Round 6
// 994.433 us; speedup vs baseline: 1.8146x; 1.0446x over previous
//
#include <hip/hip_runtime.h>
#include <hip/hip_bf16.h>
#include <cstdint>

using bf16 = __hip_bfloat16;
typedef __attribute__((ext_vector_type(8))) short bfrag;   // 8 x bf16 (4 VGPRs)
typedef __attribute__((ext_vector_type(4))) float ffrag;   // 4 x f32 acc

#define DEV __device__ __forceinline__

DEV float wred_sum(float v) {
#pragma unroll
  for (int o = 32; o > 0; o >>= 1) v += __shfl_xor(v, o, 64);
  return v;
}
DEV float bred_sum(float v) {
  __shared__ float r[4];
  int w = threadIdx.x >> 6, l = threadIdx.x & 63;
  v = wred_sum(v);
  __syncthreads();
  if (l == 0) r[w] = v;
  __syncthreads();
  return r[0] + r[1] + r[2] + r[3];
}
DEV float gelu_f(float x) {  // jax.nn.gelu approximate=True
  float x3 = x * x * x;
  return 0.5f * x * (1.0f + tanhf(0.7978845608028654f * (x + 0.044715f * x3)));
}

// ---------------------------------------------------------------- GEMM (NT)
// C[m,n] = sum_k A[m,k] * B[n,k]
struct GemmP {
  const bf16* A; const bf16* A2; const bf16* B; void* C; void* C2;
  const float* bias;
  int K, lda, ldb, ldc, inner, mode, zBshift, c2z, kSplit;
  long sA0, sA1, sB0, sB1, sC0, sC1, sb0, sb1;
  float scale;
};
// modes: 0 bf16 | 1 f32 | 3 bf16 gelu | 4 bf16 elu+1 | 6 bf16 exp(v-16)
static GemmP gp0() {
  GemmP g;
  g.A = nullptr; g.A2 = nullptr; g.B = nullptr; g.C = nullptr; g.C2 = nullptr;
  g.bias = nullptr;
  g.K = 0; g.lda = 0; g.ldb = 0; g.ldc = 0; g.inner = 1; g.mode = 0;
  g.zBshift = 0; g.c2z = -1; g.kSplit = 1 << 30;
  g.sA0 = 0; g.sA1 = 0; g.sB0 = 0; g.sB1 = 0; g.sC0 = 0; g.sC1 = 0;
  g.sb0 = 0; g.sb1 = 0; g.scale = 1.f;
  return g;
}

// LDS bank-conflict swizzle (R5, verified: SQ_LDS_BANK_CONFLICT -> 0):
// row r stores its four 16-B chunks permuted by c ^= (r>>1)&3; staging picks
// the matching global chunk per lane, fragment read applies the same XOR.
template <int BM, int BN, int WM, int WN, bool SPLIT>
__global__ __launch_bounds__(256)
void gemm_nt(GemmP p) {
  constexpr int TI = BM / (WM * 16), TJ = BN / (WN * 16);
  __shared__ bf16 smem[(BM + BN) * 32];
  const int tid = threadIdx.x;
  const int z = blockIdx.z;
  const int z0 = z % p.inner, z1 = z / p.inner;
  const long zB = (long)(z1 >> p.zBshift);
  const bf16* A = p.A + (long)z0 * p.sA0 + (long)z1 * p.sA1;
  const bf16* Bp = p.B + (long)z0 * p.sB0 + zB * p.sB1;
  const int m0 = blockIdx.x * BM, n0 = blockIdx.y * BN;
  const int wave = tid >> 6, lane = tid & 63;
  const int wrow = wave / WN, wcol = wave % WN;
  const int fr = lane & 15, quad = lane >> 4;
  const int swz = (quad ^ ((fr >> 1) & 3)) * 8;
  ffrag acc[TI][TJ] = {};
  constexpr int CH_A = BM * 4;
  constexpr int NIT = (BM + BN) * 4 / 256;
  for (int k0 = 0; k0 < p.K; k0 += 32) {
    const bf16* Asrc = A;
    int kc = k0;
    if constexpr (SPLIT) {
      if (k0 >= p.kSplit) { Asrc = p.A2; kc = k0 - p.kSplit; }
    }
#pragma unroll
    for (int it = 0; it < NIT; ++it) {
      int idx = it * 256 + tid;
      const bf16* g;
      if (idx < CH_A) {
        int r = idx >> 2, c = (idx & 3) ^ ((idx >> 3) & 3);
        g = Asrc + (long)(m0 + r) * p.lda + kc + c * 8;
      } else {
        int j = idx - CH_A;
        int r = j >> 2, c = (j & 3) ^ ((j >> 3) & 3);
        g = Bp + (long)(n0 + r) * p.ldb + k0 + c * 8;
      }
      __builtin_amdgcn_global_load_lds(
          (const __attribute__((address_space(1))) void*)g,
          (__attribute__((address_space(3))) void*)(smem + idx * 8), 16, 0, 0);
    }
    __syncthreads();
    bfrag af[TI], bfb[TJ];
#pragma unroll
    for (int t = 0; t < TI; ++t)
      af[t] = *(const bfrag*)(smem + ((wrow * (TI * 16) + t * 16 + fr) * 32 + swz));
#pragma unroll
    for (int t = 0; t < TJ; ++t)
      bfb[t] = *(const bfrag*)(smem + (BM * 32 + (wcol * (TJ * 16) + t * 16 + fr) * 32 + swz));
#pragma unroll
    for (int ti = 0; ti < TI; ++ti)
#pragma unroll
      for (int tj = 0; tj < TJ; ++tj)
        acc[ti][tj] = __builtin_amdgcn_mfma_f32_16x16x32_bf16(af[ti], bfb[tj], acc[ti][tj], 0, 0, 0);
    __syncthreads();
  }
  const int mbase = m0 + wrow * (TI * 16), nbase = n0 + wcol * (TJ * 16);
  void* Cb = p.C;
  long zc = (long)z0 * p.sC0 + (long)z1 * p.sC1;
  if (z == p.c2z) { Cb = p.C2; zc = 0; }
  const long zb = (long)z0 * p.sb0 + zB * p.sb1;
#pragma unroll
  for (int ti = 0; ti < TI; ++ti) {
#pragma unroll
    for (int tj = 0; tj < TJ; ++tj) {
#pragma unroll
      for (int r = 0; r < 4; ++r) {
        int m = mbase + ti * 16 + quad * 4 + r;
        int n = nbase + tj * 16 + fr;
        float v = acc[ti][tj][r] * p.scale;
        if (p.bias) v += p.bias[zb + n];
        long ci = zc + (long)m * p.ldc + n;
        if (p.mode == 0) ((bf16*)Cb)[ci] = __float2bfloat16(v);
        else if (p.mode == 1) ((float*)Cb)[ci] = v;
        else if (p.mode == 3) ((bf16*)Cb)[ci] = __float2bfloat16(gelu_f(v));
        else if (p.mode == 4) ((bf16*)Cb)[ci] = __float2bfloat16(v > 0.f ? v + 1.f : __expf(v));
        else ((bf16*)Cb)[ci] = __float2bfloat16(__expf(v - 16.f));
      }
    }
  }
}

// cfg 0: 128x128 | 1: 128x64 | 2: 64x64 | 3: 64x64 split-A
static void launch_gemm(hipStream_t st, int cfg, int M, int N, int batch, const GemmP& g) {
  dim3 bs(256);
  if (cfg == 0)      gemm_nt<128, 128, 2, 2, false><<<dim3(M / 128, N / 128, batch), bs, 0, st>>>(g);
  else if (cfg == 1) gemm_nt<128, 64, 2, 2, false><<<dim3(M / 128, N / 64, batch), bs, 0, st>>>(g);
  else if (cfg == 2) gemm_nt<64, 64, 2, 2, false><<<dim3(M / 64, N / 64, batch), bs, 0, st>>>(g);
  else               gemm_nt<64, 64, 2, 2, true><<<dim3(M / 64, N / 64, batch), bs, 0, st>>>(g);
}

// ---------------------------------------------------------------- prep (all weight transposes)
// grid (32, 64, 42); src[R][C] f32 -> dst[C][R] bf16, demuxed on z
__global__ void prep_k(const float* w_qkvo, const float* sub_w1, const float* sub_w2,
                       const float* conv_pw, const float* fus_w, const float* r1_w1,
                       const float* r2_w1, const float* phi_w, const float* psi_w,
                       const float* phi_b, const float* psi_b,
                       bf16* wt, bf16* fuswt, bf16* r1w1t, bf16* r2w1t,
                       bf16* phiwt, bf16* psiwt, float* phipsib, bf16* vtp1) {
  int z = blockIdx.z;
  int bx = blockIdx.x, by = blockIdx.y;
  int tx = threadIdx.x & 31, ty = threadIdx.x >> 5;
  const float* src; bf16* dst; int R, C;
  if (z < 33) {
    if (by >= 32) return;
    src = z < 16 ? w_qkvo + (long)z * 1048576
        : z < 24 ? sub_w1 + (long)(z - 16) * 1048576
        : z < 32 ? sub_w2 + (long)(z - 24) * 1048576
                 : conv_pw;
    dst = wt + (long)z * 1048576; R = 1024; C = 1024;
  } else if (z == 33) {
    src = fus_w; dst = fuswt; R = 2048; C = 1024;
  } else if (z == 34) {
    if (bx >= 16 || by >= 32) return;
    src = r1_w1; dst = r1w1t; R = 1024; C = 512;
  } else if (z < 39) {
    if (bx >= 8 || by >= 32) return;
    src = r2_w1 + (long)(z - 35) * 262144; dst = r2w1t + (long)(z - 35) * 262144;
    R = 1024; C = 256;
  } else if (z < 41) {
    if (bx >= 8 || by >= 2) return;
    src = (z == 39) ? phi_w : psi_w; dst = (z == 39) ? phiwt : psiwt; R = 64; C = 256;
  } else {
    if (by == 0) {  // ones row (performer ksum trick): slice bx of VTP1
      for (int c = threadIdx.x; c < 1024; c += 256)
        vtp1[(long)bx * 131072 + 65536 + c] = __float2bfloat16(1.0f);
    } else if (by == 1 && bx == 0) {
      for (int i = threadIdx.x; i < 512; i += 256)
        phipsib[i] = i < 256 ? phi_b[i] : psi_b[i - 256];
    }
    return;
  }
  __shared__ float t[32][33];
  int c0 = bx * 32, r0 = by * 32;
#pragma unroll
  for (int i = 0; i < 32; i += 8)
    t[ty + i][tx] = src[(long)(r0 + ty + i) * C + c0 + tx];
  __syncthreads();
#pragma unroll
  for (int i = 0; i < 32; i += 8)
    dst[(long)(c0 + ty + i) * R + r0 + tx] = __float2bfloat16(t[tx][ty + i]);
}

// per-row: x->bf16, depthwise conv, token-importance dot — one x pass
__global__ void xprep_k(const float* x, const float* dw, const float* spw, const float* spb,
                        bf16* xb, bf16* t1, float* tokimp) {
  long row = blockIdx.x;                 // 2048 rows
  int s = (int)(row & 1023);
  int tid = threadIdx.x;
  const float* xr = x + row * 1024;
  float dot = 0.f;
#pragma unroll
  for (int i = 0; i < 4; ++i) {
    int d = tid + i * 256;
    float xv = xr[d];
    xb[row * 1024 + d] = __float2bfloat16(xv);
    float a = xv * dw[1024 + d];
    if (s > 0) a += xr[d - 1024] * dw[d];
    if (s < 1023) a += xr[d + 1024] * dw[2048 + d];
    t1[row * 1024 + d] = __float2bfloat16(a);
    dot += xv * spw[d];
  }
  float tot = bred_sum(dot);
  if (tid == 0) tokimp[row] = tot + spb[0];
}

// bf16 strided [z](R x C, row stride rs) -> bf16 out + z*ldz, out[c*R + r]
__global__ void transpose_bf16_k(const bf16* in, bf16* outp, int R, int C, int rs,
                                 int inner, int inner2, long is0, long is1, long is2,
                                 long ldz) {
  __shared__ bf16 t[32][33];
  int z = blockIdx.z;
  int z0 = z % inner; int zr = z / inner;
  int z1 = zr % inner2; int z2 = zr / inner2;
  long zo = (long)z0 * is0 + (long)z1 * is1 + (long)z2 * is2;
  int c0 = blockIdx.x * 32, r0 = blockIdx.y * 32;
  int tx = threadIdx.x & 31, ty = threadIdx.x >> 5;
#pragma unroll
  for (int i = 0; i < 32; i += 8)
    t[ty + i][tx] = in[zo + (long)(r0 + ty + i) * rs + c0 + tx];
  __syncthreads();
  long ob = (long)z * ldz;
#pragma unroll
  for (int i = 0; i < 32; i += 8)
    outp[ob + (long)(c0 + ty + i) * R + r0 + tx] = t[tx][ty + i];
}

// ones row 64 of 64 slices [128][1024] (attention denominator trick)
__global__ void vtones_k(bf16* vt) {
  int i = blockIdx.x * 256 + threadIdx.x;
  int z = i >> 10, c = i & 1023;
  vt[(long)z * 131072 + 65536 + c] = __float2bfloat16(1.0f);
}

// out[((b*1024+s)*1024) + h*64 + n] = in[(h+16b)*131072 + s*128 + n] / (in[..64]+eps)
__global__ void norm_k(const bf16* in, bf16* outp, float eps) {
  int r = blockIdx.x * 4 + (threadIdx.x >> 6);   // z*1024 + s
  int n = threadIdx.x & 63;
  int z = r >> 10, s = r & 1023;
  int h = z & 15, b = z >> 4;
  const bf16* ip = in + (long)r * 128;
  float den = __bfloat162float(ip[64]) + eps;
  float v = __bfloat162float(ip[n]);
  outp[((long)(b * 1024 + s) * 1024) + h * 64 + n] = __float2bfloat16(v / den);
}

// LN + act, single global read (register cache), N <= 1024
__global__ void ln_act_k(const void* in, const float* gamma, const float* beta,
                         bf16* outp, int N, int act, int rows_per_seg, int in_bf16) {
  long row = blockIdx.x;
  int tid = threadIdx.x;
  const bf16* ib = (const bf16*)in;
  const float* iff = (const float*)in;
  float vc[4];
  float ls = 0.f;
  int i = 0;
  for (int c = tid; c < N; c += 256, ++i) {
    float v = in_bf16 ? __bfloat162float(ib[row * N + c]) : iff[row * N + c];
    vc[i] = v; ls += v;
  }
  float mean = bred_sum(ls) / N;
  float lv = 0.f;
  i = 0;
  for (int c = tid; c < N; c += 256, ++i) { float d = vc[i] - mean; lv += d * d; }
  float rstd = rsqrtf(bred_sum(lv) / N + 1e-5f);
  long go = (row / rows_per_seg) * (long)N;
  const float* gp = gamma + go;
  const float* bp = beta + go;
  i = 0;
  for (int c = tid; c < N; c += 256, ++i) {
    float v = (vc[i] - mean) * rstd * gp[c] + bp[c];
    v = act ? gelu_f(v) : fmaxf(v, 0.f);
    outp[row * N + c] = __float2bfloat16(v);
  }
}

__global__ void topk_k(const float* timp, int* outp) {
  __shared__ float vals[1024];
  __shared__ float wv[4];
  __shared__ int wi[4];
  int b = blockIdx.x, tid = threadIdx.x;
  for (int c = tid; c < 1024; c += 256) vals[c] = timp[b * 1024 + c];
  __syncthreads();
  for (int t = 0; t < 10; ++t) {
    float bv = -3.0e38f; int bi = 1 << 30;
    for (int c = tid; c < 1024; c += 256) {
      float v = vals[c];
      if (v > bv || (v == bv && c < bi)) { bv = v; bi = c; }
    }
#pragma unroll
    for (int o = 32; o > 0; o >>= 1) {
      float ov = __shfl_xor(bv, o, 64); int oi = __shfl_xor(bi, o, 64);
      if (ov > bv || (ov == bv && oi < bi)) { bv = ov; bi = oi; }
    }
    int w = tid >> 6, l = tid & 63;
    if (l == 0) { wv[w] = bv; wi[w] = bi; }
    __syncthreads();
    if (tid == 0) {
      float fv = wv[0]; int fi = wi[0];
      for (int ww = 1; ww < 4; ++ww)
        if (wv[ww] > fv || (wv[ww] == fv && wi[ww] < fi)) { fv = wv[ww]; fi = wi[ww]; }
      outp[b * 16 + t] = fi;
      vals[fi] = -3.0e38f;
    }
    __syncthreads();
  }
}

// stage-1 V column sums: 512 blocks, partials [32][16][64]
__global__ void vsum_k(const bf16* v, float* vsump) {
  __shared__ float red[4][64];
  int zz = blockIdx.x;
  int z = zz >> 4, slab = zz & 15;
  int b = z >> 4, h = z & 15;
  const bf16* vp = v + (long)b * 1048576 + h * 64;
  int d = threadIdx.x & 63, sg = threadIdx.x >> 6;
  float s = 0.f;
#pragma unroll
  for (int i = 0; i < 16; ++i) {
    int srow = slab * 64 + sg * 16 + i;
    s += __bfloat162float(vp[(long)srow * 1024 + d]);
  }
  red[sg][d] = s;
  __syncthreads();
  if (sg == 0) vsump[(long)zz * 64 + d] = red[0][d] + red[1][d] + red[2][d] + red[3][d];
}

// expert-0 sparse attention, algebraically reduced
__global__ void sparse_attn_k(const bf16* q, const bf16* k, const bf16* v,
                              const float* vsump, const int* topidx, bf16* merged) {
  __shared__ float kt[10][64], vt[10][64], vs[64], vts[64];
  int z = blockIdx.y, b = z >> 4, h = z & 15;
  int tid = threadIdx.x;
  const int* tix = topidx + b * 16;
  for (int t = tid; t < 640; t += 256) {
    int tt = t >> 6, d = t & 63;
    long src = ((long)b * 1024 + tix[tt]) * 1024 + h * 64 + d;
    kt[tt][d] = __bfloat162float(k[src]);
    vt[tt][d] = __bfloat162float(v[src]);
  }
  if (tid < 64) {
    float s = 0.f;
#pragma unroll
    for (int p = 0; p < 16; ++p) s += vsump[((long)z * 16 + p) * 64 + tid];
    vs[tid] = s;
  }
  __syncthreads();
  if (tid < 64) {
    float s = 0.f;
#pragma unroll
    for (int t = 0; t < 10; ++t) s += vt[t][tid];
    vts[tid] = s;
  }
  __syncthreads();
  int wave = tid >> 6, lane = tid & 63;
  int sq = blockIdx.x * 4 + wave;
  long qi = ((long)b * 1024 + sq) * 1024 + h * 64 + lane;
  float qd = __bfloat162float(q[qi]);
  float sc[10];
#pragma unroll
  for (int t = 0; t < 10; ++t) sc[t] = wred_sum(qd * kt[t][lane]) * 0.125f;
  float m = 0.f;
#pragma unroll
  for (int t = 0; t < 10; ++t) m = fmaxf(m, sc[t]);
  float e[10], se = 0.f;
#pragma unroll
  for (int t = 0; t < 10; ++t) { e[t] = __expf(sc[t] - m); se += e[t]; }
  float em = __expf(-m);
  float Z = 1014.f * em + se;
  float o = em * (vs[lane] - vts[lane]);
#pragma unroll
  for (int t = 0; t < 10; ++t) o += e[t] * vt[t][lane];
  merged[qi] = __float2bfloat16(o / Z);
}

__global__ void router1_k(const bf16* h1, const float* w, const float* bias, float* outp) {
  int row = blockIdx.x * 4 + (threadIdx.x >> 6);
  int l = threadIdx.x & 63;
  const bf16* hp = h1 + (long)row * 512;
  float a0 = 0, a1 = 0, a2 = 0, a3 = 0;
  for (int c = l; c < 512; c += 64) {
    float hv = __bfloat162float(hp[c]);
    const float* wp = w + c * 4;
    a0 += hv * wp[0]; a1 += hv * wp[1]; a2 += hv * wp[2]; a3 += hv * wp[3];
  }
  a0 = wred_sum(a0); a1 = wred_sum(a1); a2 = wred_sum(a2); a3 = wred_sum(a3);
  a0 += bias[0]; a1 += bias[1]; a2 += bias[2]; a3 += bias[3];
  float m = fmaxf(fmaxf(a0, a1), fmaxf(a2, a3));
  float e0 = __expf(a0 - m), e1 = __expf(a1 - m), e2 = __expf(a2 - m), e3 = __expf(a3 - m);
  float inv = 1.f / (e0 + e1 + e2 + e3);
  if (l == 0) {
    float* op = outp + (long)row * 4;
    op[0] = e0 * inv; op[1] = e1 * inv; op[2] = e2 * inv; op[3] = e3 * inv;
  }
}

__global__ void router2_k(const bf16* h2, const float* w, const float* bias, float* outp,
                          int rows_per_seg) {
  int row = blockIdx.x * 4 + (threadIdx.x >> 6);
  int l = threadIdx.x & 63;
  int seg = row / rows_per_seg;
  const float* wp = w + (long)seg * 512;
  const float* bp = bias + (long)seg * 2;
  const bf16* hp = h2 + (long)row * 256;
  float a0 = 0, a1 = 0;
  for (int c = l; c < 256; c += 64) {
    float hv = __bfloat162float(hp[c]);
    a0 += hv * wp[c * 2]; a1 += hv * wp[c * 2 + 1];
  }
  a0 = wred_sum(a0); a1 = wred_sum(a1);
  a0 += bp[0]; a1 += bp[1];
  float m = fmaxf(a0, a1);
  float e0 = __expf(a0 - m), e1 = __expf(a1 - m);
  float inv = 1.f / (e0 + e1);
  if (l == 0) { outp[(long)row * 2] = e0 * inv; outp[(long)row * 2 + 1] = e1 * inv; }
}

// final: out[m,n] = sum_z p1[m][z/2] * p2[z/2][m][z&1] * part[z][m][n]
__global__ void combine_k(const bf16* part, const float* p1, const float* p2, float* outp) {
  long i = (long)blockIdx.x * 256 + threadIdx.x;
  long m = i >> 10;
  float acc = 0.f;
#pragma unroll
  for (int zz = 0; zz < 8; ++zz) {
    int e = zz >> 1, j = zz & 1;
    float w = p1[m * 4 + e] * p2[(long)e * 4096 + m * 2 + j];
    acc += w * __bfloat162float(part[(long)zz * 2097152 + i]);
  }
  outp[i] = acc;
}

// ---------------------------------------------------------------- host
extern "C" void kernel_launch(void* const* d_in, const int* in_sizes, int n_in,
                              void* d_out, int out_size, void* d_ws, size_t ws_size,
                              hipStream_t stream) {
  const float* x = (const float*)d_in[0];
  const float* w_qkvo = (const float*)d_in[1];
  const float* b_qkvo = (const float*)d_in[2];
  const float* sp_w = (const float*)d_in[3];
  const float* sp_b = (const float*)d_in[4];
  const float* phi_w = (const float*)d_in[5];
  const float* phi_b = (const float*)d_in[6];
  const float* psi_w = (const float*)d_in[7];
  const float* psi_b = (const float*)d_in[8];
  const float* conv_dw = (const float*)d_in[9];
  const float* conv_pw = (const float*)d_in[10];
  const float* fus_w = (const float*)d_in[11];
  const float* fus_b = (const float*)d_in[12];
  const float* sub_w1 = (const float*)d_in[13];
  const float* sub_b1 = (const float*)d_in[14];
  const float* sub_g = (const float*)d_in[15];
  const float* sub_be = (const float*)d_in[16];
  const float* sub_w2 = (const float*)d_in[17];
  const float* sub_b2 = (const float*)d_in[18];
  const float* r1_w1 = (const float*)d_in[19];
  const float* r1_b1 = (const float*)d_in[20];
  const float* r1_g = (const float*)d_in[21];
  const float* r1_be = (const float*)d_in[22];
  const float* r1_w2 = (const float*)d_in[23];
  const float* r1_b2 = (const float*)d_in[24];
  const float* r2_w1 = (const float*)d_in[25];
  const float* r2_b1 = (const float*)d_in[26];
  const float* r2_g = (const float*)d_in[27];
  const float* r2_be = (const float*)d_in[28];
  const float* r2_w2 = (const float*)d_in[29];
  const float* r2_b2 = (const float*)d_in[30];
  (void)in_sizes; (void)n_in; (void)ws_size; (void)out_size;

  char* ws = (char*)d_ws;
  size_t off = 0;
  auto take = [&](size_t bytes) { void* p = ws + off; off += (bytes + 255) & ~(size_t)255; return p; };

  const long EL2M = 2097152;  // 2048*1024
  const long EL1M = 1048576;  // 1024*1024

  bf16* XB      = (bf16*)take((size_t)EL2M * 2);
  bf16* WQKVOT  = (bf16*)take((size_t)16 * EL1M * 2);
  bf16* SUBW1T  = (bf16*)take((size_t)8 * EL1M * 2);
  bf16* SUBW2T  = (bf16*)take((size_t)8 * EL1M * 2);
  bf16* CONVPWT = (bf16*)take((size_t)EL1M * 2);
  bf16* FUSWT   = (bf16*)take((size_t)EL2M * 2);
  bf16* R1W1T   = (bf16*)take((size_t)512 * 1024 * 2);
  bf16* R2W1T   = (bf16*)take((size_t)4 * 256 * 1024 * 2);
  bf16* PHIWT   = (bf16*)take((size_t)16384 * 2);
  bf16* PSIWT   = (bf16*)take((size_t)16384 * 2);
  float* PHIPSIB = (float*)take((size_t)512 * 4);
  bf16* QKVB    = (bf16*)take((size_t)12 * EL2M * 2);  // + MERGED4 adjacent -> sub arena
  bf16* MERGED4 = (bf16*)take((size_t)4 * EL2M * 2);
  bf16* VTP1    = (bf16*)take((size_t)32 * 128 * 1024 * 2);  // also performer TNUM
  bf16* EO      = (bf16*)take((size_t)4 * EL2M * 2);
  bf16* T1      = (bf16*)take((size_t)EL2M * 2);       // survives SC phase
  bf16* ARENA   = (bf16*)take((size_t)64 * 1024 * 1024);
  float* PROBS1 = (float*)take((size_t)2048 * 4 * 4);
  float* PROBS2 = (float*)take((size_t)4 * 2048 * 2 * 4);
  float* TOKIMP = (float*)take((size_t)2048 * 4);
  int*   TOPIDX = (int*)take((size_t)2 * 16 * 4);
  float* VSUMP  = (float*)take((size_t)32 * 16 * 64 * 4);

  // ARENA phase 1 (performer):
  bf16* QPHI  = ARENA;                       // [32][1024][256]
  bf16* KPSI  = ARENA + 8388608;             // [32][1024][256]
  bf16* KPSIT = ARENA + 16777216;            // [32][256][1024]
  bf16* KVTX  = ARENA + 25165824;            // [32][128][256] (row64 = ksum)
  // ARENA phase 2 (attention): SC = full 64 MB
  bf16* SC = ARENA;                          // [32][1024][1024]
  // ARENA phase 3 (late, after SC dead):
  bf16* SUB2F = ARENA;                       // [8][2048][1024] bf16 partials
  float* F32TMP = (float*)(ARENA + 16777216);  // 8 MB
  bf16* H1 = ARENA + 20971520;               // [2048][512]
  bf16* H2 = ARENA + 22020096;               // [4*2048][256]
  bf16* AO = ARENA + 24117248;               // [2048][1024]
  bf16* XC = ARENA + 26214400;               // [2048][1024]
  // QKVB slice reuse (dead after sparse/performer phases):
  bf16* TNUM23 = QKVB;                       // slices 0-1: [32][1024][128] PV numerator+den
  bf16* VT23   = QKVB + 2 * EL2M;            // slices 2-5: [64][128][1024] V^T (+ones row 64)
  // sub arena (aliases QKVB+MERGED4, dead by then):
  bf16* SUB1A = QKVB;                        // [8][2048][1024]
  bf16* SUB1B = QKVB + 16777216;             // [8][2048][1024]

  // ---- phase 0: weights + x prep ----
  prep_k<<<dim3(32, 64, 42), 256, 0, stream>>>(w_qkvo, sub_w1, sub_w2, conv_pw, fus_w,
                                               r1_w1, r2_w1, phi_w, psi_w, phi_b, psi_b,
                                               WQKVOT, FUSWT, R1W1T, R2W1T,
                                               PHIWT, PSIWT, PHIPSIB, VTP1);
  xprep_k<<<2048, 256, 0, stream>>>(x, conv_dw, sp_w, sp_b, XB, T1, TOKIMP);

  // ---- QKV for all experts, one batch-12 GEMM ----
  {
    GemmP g = gp0();
    g.A = XB; g.lda = 1024;
    g.B = WQKVOT; g.ldb = 1024; g.sB0 = EL1M; g.sB1 = 4 * EL1M;
    g.C = QKVB; g.ldc = 1024; g.sC0 = EL2M; g.sC1 = 3 * EL2M;
    g.bias = b_qkvo; g.sb0 = 1024; g.sb1 = 4096;
    g.K = 1024; g.inner = 3; g.mode = 0;
    launch_gemm(stream, 0, 2048, 1024, 12, g);
  }

  // ---- expert 0: sparse attention ----
  topk_k<<<2, 256, 0, stream>>>(TOKIMP, TOPIDX);
  vsum_k<<<512, 256, 0, stream>>>(QKVB + 2 * EL2M, VSUMP);
  sparse_attn_k<<<dim3(256, 32), 256, 0, stream>>>(QKVB, QKVB + EL2M, QKVB + 2 * EL2M,
                                                   VSUMP, TOPIDX, MERGED4);

  // ---- expert 1: performer ----
  {  // phi(Q) and psi(K) in one batch-64 GEMM
    GemmP g = gp0();
    g.A = QKVB + 3 * EL2M; g.lda = 1024; g.sA0 = 64; g.sA1 = EL1M;
    g.B = PHIWT; g.ldb = 64; g.sB1 = 16384; g.zBshift = 1;
    g.C = QPHI; g.ldc = 256; g.sC0 = 262144; g.sC1 = 16 * 262144L;
    g.bias = PHIPSIB; g.sb1 = 256;
    g.K = 64; g.inner = 16; g.mode = 4;
    launch_gemm(stream, 2, 1024, 256, 64, g);
  }
  transpose_bf16_k<<<dim3(8, 32, 32), 256, 0, stream>>>(KPSI, KPSIT, 1024, 256, 256,
                                                        32, 1, 262144, 0, 0, 262144);
  transpose_bf16_k<<<dim3(2, 32, 32), 256, 0, stream>>>(QKVB + 5 * EL2M, VTP1, 1024, 64, 1024,
                                                        16, 2, 64, EL1M, 0, 131072);
  {  // KVTX[m,d] = sum_l VTP1[m,l]*KPSIT[d,l]; row 64 = ksum
    GemmP g = gp0();
    g.A = VTP1; g.lda = 1024; g.sA0 = 131072; g.sA1 = 16 * 131072L;
    g.B = KPSIT; g.ldb = 1024; g.sB0 = 262144; g.sB1 = 16 * 262144L;
    g.C = KVTX; g.ldc = 256; g.sC0 = 32768; g.sC1 = 16 * 32768L;
    g.K = 1024; g.inner = 16; g.mode = 0;
    launch_gemm(stream, 2, 128, 256, 32, g);
  }
  {  // num+den: N=128 against KVTX (col 64 = qphi.ksum) -> TNUM (aliases VTP1)
    GemmP g = gp0();
    g.A = QPHI; g.lda = 256; g.sA0 = 262144; g.sA1 = 16 * 262144L;
    g.B = KVTX; g.ldb = 256; g.sB0 = 32768; g.sB1 = 16 * 32768L;
    g.C = VTP1; g.ldc = 128; g.sC0 = 131072; g.sC1 = 16 * 131072L;
    g.K = 256; g.inner = 16; g.mode = 0;
    launch_gemm(stream, 2, 1024, 128, 32, g);
  }
  norm_k<<<8192, 256, 0, stream>>>(VTP1, MERGED4 + EL2M, 1e-8f);

  // ---- V^T (+ones row) for experts 2,3 into dead QKVB slices 2-5 ----
  transpose_bf16_k<<<dim3(2, 32, 64), 256, 0, stream>>>(QKVB + 8 * EL2M, VT23, 1024, 64, 1024,
                                                        16, 2, 64, EL1M, 3 * EL2M, 131072);
  vtones_k<<<256, 256, 0, stream>>>(VT23);

  // ---- experts 2 & 3: softmax attention (exp fused in scores, sum via ones row) ----
  for (int e = 2; e <= 3; ++e) {
    const bf16* q = QKVB + (size_t)(e * 3 + 0) * EL2M;
    const bf16* k = QKVB + (size_t)(e * 3 + 1) * EL2M;
    {  // SC = exp(q k^T * scale - 16)
      GemmP g = gp0();
      g.A = q; g.lda = 1024; g.sA0 = 64; g.sA1 = EL1M;
      g.B = k; g.ldb = 1024; g.sB0 = 64; g.sB1 = EL1M;
      g.C = SC; g.ldc = 1024; g.sC0 = EL1M; g.sC1 = 16 * EL1M;
      g.K = 64; g.inner = 16; g.scale = 0.125f; g.mode = 6;
      launch_gemm(stream, 0, 1024, 1024, 32, g);
    }
    {  // expSC @ [V^T; ones] -> numerator cols 0..63, denominator col 64
      GemmP g = gp0();
      g.A = SC; g.lda = 1024; g.sA0 = EL1M; g.sA1 = 16 * EL1M;
      g.B = VT23 + (size_t)(e - 2) * 32 * 131072; g.ldb = 1024; g.sB0 = 131072; g.sB1 = 16 * 131072L;
      g.C = TNUM23; g.ldc = 128; g.sC0 = 131072; g.sC1 = 16 * 131072L;
      g.K = 1024; g.inner = 16; g.mode = 0;
      launch_gemm(stream, 2, 1024, 128, 32, g);
    }
    norm_k<<<8192, 256, 0, stream>>>(TNUM23, MERGED4 + (size_t)e * EL2M, 0.f);
  }

  // ---- batch-4 output projection (z=3 -> AO) ----
  {
    GemmP g = gp0();
    g.A = MERGED4; g.lda = 1024; g.sA1 = EL2M;
    g.B = WQKVOT + 3 * EL1M; g.ldb = 1024; g.sB1 = 4 * EL1M;
    g.C = EO; g.ldc = 1024; g.sC1 = EL2M;
    g.C2 = AO; g.c2z = 3;
    g.bias = b_qkvo + 3 * 1024; g.sb1 = 4096;
    g.K = 1024; g.mode = 0;
    launch_gemm(stream, 0, 2048, 1024, 4, g);
  }

  // ---- conv branch + fusion ----
  {
    GemmP g = gp0();
    g.A = T1; g.lda = 1024;
    g.B = CONVPWT; g.ldb = 1024;
    g.C = XC; g.ldc = 1024;
    g.K = 1024; g.mode = 3;
    launch_gemm(stream, 2, 2048, 1024, 1, g);
  }
  {  // fusion: A = [AO | XC], K=2048 (SPLIT variant)
    GemmP g = gp0();
    g.A = AO; g.A2 = XC; g.kSplit = 1024; g.lda = 1024;
    g.B = FUSWT; g.ldb = 2048;
    g.C = EO + 3 * EL2M; g.ldc = 1024;
    g.bias = fus_b; g.K = 2048; g.mode = 0;
    launch_gemm(stream, 3, 2048, 1024, 1, g);
  }

  // ---- routers ----
  {
    GemmP g = gp0();
    g.A = XB; g.lda = 1024;
    g.B = R1W1T; g.ldb = 1024;
    g.C = F32TMP; g.ldc = 512;
    g.bias = r1_b1; g.K = 1024; g.mode = 1;
    launch_gemm(stream, 2, 2048, 512, 1, g);
  }
  ln_act_k<<<2048, 256, 0, stream>>>(F32TMP, r1_g, r1_be, H1, 512, 0, 2048, 0);
  router1_k<<<512, 256, 0, stream>>>(H1, r1_w2, r1_b2, PROBS1);
  {
    GemmP g = gp0();
    g.A = EO; g.lda = 1024; g.sA1 = EL2M;
    g.B = R2W1T; g.ldb = 1024; g.sB1 = 262144;
    g.C = F32TMP; g.ldc = 256; g.sC1 = 2048 * 256;
    g.bias = r2_b1; g.sb1 = 256; g.K = 1024; g.mode = 1;
    launch_gemm(stream, 2, 2048, 256, 4, g);
  }
  ln_act_k<<<8192, 256, 0, stream>>>(F32TMP, r2_g, r2_be, H2, 256, 0, 2048, 0);
  router2_k<<<2048, 256, 0, stream>>>(H2, r2_w2, r2_b2, PROBS2, 2048);

  // ---- sub-experts: batch-8 everything ----
  {  // sub1: z = j + 2*i
    GemmP g = gp0();
    g.A = EO; g.lda = 1024; g.sA1 = EL2M;
    g.B = SUBW1T; g.ldb = 1024; g.sB0 = EL1M; g.sB1 = 2 * EL1M;
    g.C = SUB1A; g.ldc = 1024; g.sC0 = EL2M; g.sC1 = 2 * EL2M;
    g.bias = sub_b1; g.sb0 = 1024; g.sb1 = 2048;
    g.K = 1024; g.inner = 2; g.mode = 0;
    launch_gemm(stream, 0, 2048, 1024, 8, g);
  }
  ln_act_k<<<16384, 256, 0, stream>>>(SUB1A, sub_g, sub_be, SUB1B, 1024, 1, 2048, 1);
  {  // sub2 partials (bias folded)
    GemmP g = gp0();
    g.A = SUB1B; g.lda = 1024; g.sA1 = EL2M;
    g.B = SUBW2T; g.ldb = 1024; g.sB1 = EL1M;
    g.C = SUB2F; g.ldc = 1024; g.sC1 = EL2M;
    g.bias = sub_b2; g.sb1 = 1024;
    g.K = 1024; g.mode = 0;
    launch_gemm(stream, 0, 2048, 1024, 8, g);
  }
  combine_k<<<8192, 256, 0, stream>>>(SUB2F, PROBS1, PROBS2, (float*)d_out);
}